// Round 15
// baseline (37.239 us; speedup 1.0000x reference)
//
#include <hip/hip_runtime.h>
#include <hip/hip_fp16.h>

#define G_ 8
#define C_ 64
#define K_ 9
#define H_ 100
#define W_ 160
#define TW_ 8
#define TH_ 8
#define HALO_ 4
#define SW_ (TW_ + 2*HALO_)       // 16 staged cols
#define SH_ (TH_ + 2*HALO_)       // 16 staged rows
#define NREC_ (SW_ * SH_)         // 256 records
#define RECU_ 17                  // 136 B record stride, in u64 units
#define LDSU_ (NREC_ * RECU_)     // 4352 u64 = 34816 B -> 4 blocks/CU

// R13/R14 code with 8x8 tiles: 2080 blocks of 256 threads, 34.8 KB LDS ->
// 4 blocks/CU (16 waves steady, same as R13) but the dispatch tail shrinks
// from 272/1040 (26%) to 32/2080 (1.5%) of work units. Phase A (softmax +
// offsets) hoisted before the staging barrier; staging f32->f16 swizzled
// 136-B-stride records; phase B loads-first gather; exact global-f32
// fallback for rare out-of-halo taps. All register arrays statically
// indexed (R11/R12 scratch-spill lesson).
__global__ __launch_bounds__(256, 4) void dcn_lds_kernel(
    const float* __restrict__ x,      // [H,W,G*C] f32
    const float* __restrict__ offset, // [H,W,G*K*2]
    const float* __restrict__ mask,   // [H,W,G*K]
    float* __restrict__ out)          // [H,W,G*C]
{
    __shared__ unsigned long long sm[LDSU_];
    const int bid = (int)blockIdx.x;
    const int g   = bid & 7;          // group -> XCD round-robin
    const int t   = bid >> 3;         // 0..259 tile id (13 rows x 20 cols)
    const int th  = t / 20, twc = t % 20;
    const int h0  = th * TH_, w0 = twc * TW_;
    const int tid = (int)threadIdx.x;

    const int p   = tid >> 2;           // 0..63 pixel in tile
    const int q   = tid & 3;            // channel quarter (32-B chunk)
    const int chb = q * 16;             // channel base
    const int hh  = h0 + (p >> 3);
    const int ww  = w0 + (p & 7);
    const bool live = (hh < H_);        // ragged bottom tile
    const int pixg = (hh * W_ + ww) * G_ + g;

    // ---- softmax + offset loads hoisted BEFORE barrier ----
    float mv[K_];
    float2 ov[K_];
    if (live) {
        const float* mptr = mask + (size_t)pixg * K_;
        float mmax = -1e30f;
#pragma unroll
        for (int k = 0; k < K_; ++k) { mv[k] = mptr[k]; mmax = fmaxf(mmax, mv[k]); }
        float msum = 0.f;
#pragma unroll
        for (int k = 0; k < K_; ++k) { mv[k] = __expf(mv[k] - mmax); msum += mv[k]; }
        const float minv = 1.f / msum;
#pragma unroll
        for (int k = 0; k < K_; ++k) mv[k] *= minv;

        const float* optr = offset + (size_t)pixg * (K_ * 2);
#pragma unroll
        for (int k = 0; k < K_; ++k) ov[k] = *(const float2*)(optr + 2 * k);
    } else {
#pragma unroll
        for (int k = 0; k < K_; ++k) { mv[k] = 0.f; ov[k] = make_float2(0.f, 0.f); }
    }

    // ---------------- stage x tile (f32 -> f16, swizzled) ----------------
    // 256 recs x 8 sub-chunks = 2048 tasks = 8 x 256
#pragma unroll
    for (int it = 0; it < 8; ++it) {
        const int task = it * 256 + tid;
        const int rec = task >> 3, sub = task & 7;   // sub = 8-float chunk
        const int i = rec >> 4, j = rec & 15;        // SW_ == 16
        const int hs = h0 - HALO_ + i, ws = w0 - HALO_ + j;
        if (hs >= 0 && hs < H_ && ws >= 0 && ws < W_) {
            const float* src = x + (size_t)(hs * W_ + ws) * (G_ * C_) + g * C_ + sub * 8;
            const float4 A = *(const float4*)src;
            const float4 B = *(const float4*)(src + 4);
            __half2 p0 = __floats2half2_rn(A.x, A.y);
            __half2 p1 = __floats2half2_rn(A.z, A.w);
            __half2 p2 = __floats2half2_rn(B.x, B.y);
            __half2 p3 = __floats2half2_rn(B.z, B.w);
            const unsigned long long lo =
                ((unsigned long long)*(unsigned*)&p1 << 32) | *(unsigned*)&p0;
            const unsigned long long hi =
                ((unsigned long long)*(unsigned*)&p3 << 32) | *(unsigned*)&p2;
            const int c = sub >> 1, hsel = sub & 1;  // 32-B chunk, 16-B half
            const int base = rec * RECU_ + ((c ^ (rec & 3)) << 2) + hsel * 2;
            sm[base]     = lo;
            sm[base + 1] = hi;
        }
    }
    __syncthreads();

    if (!live) return;

    // ---------------- phase B: loads-first gather + FMA -------------------
    __half2 acc[3][8];
#pragma unroll
    for (int gr = 0; gr < 3; ++gr)
#pragma unroll
        for (int u = 0; u < 8; ++u) acc[gr][u] = __half2(__half(0.f), __half(0.f));

#pragma unroll
    for (int k = 0; k < K_; ++k) {
        const int gr = k / 3;
        const float lh = (float)(hh + k / 3 - 1) + ov[k].x;
        const float lw = (float)(ww + k % 3 - 1) + ov[k].y;
        const float fh0 = floorf(lh), fw0 = floorf(lw);
        const float ft = lh - fh0, gt = lw - fw0;
        const int hI = (int)fh0, wI = (int)fw0;
        const float m = mv[k];

        const float wh0 = (hI >= 0  && hI < H_    ) ? (1.f - ft) * m : 0.f;
        const float wh1 = (hI >= -1 && hI < H_ - 1) ? ft * m         : 0.f;
        const float cw0 = (wI >= 0  && wI < W_    ) ? (1.f - gt)     : 0.f;
        const float cw1 = (wI >= -1 && wI < W_ - 1) ? gt             : 0.f;
        const __half2 W00 = __float2half2_rn(wh0 * cw0);
        const __half2 W01 = __float2half2_rn(wh0 * cw1);
        const __half2 W10 = __float2half2_rn(wh1 * cw0);
        const __half2 W11 = __float2half2_rn(wh1 * cw1);

        const int hc0 = min(max(hI,     0), H_ - 1);
        const int hc1 = min(max(hI + 1, 0), H_ - 1);
        const int wc0 = min(max(wI,     0), W_ - 1);
        const int wc1 = min(max(wI + 1, 0), W_ - 1);

        const bool inbox = (hI >= h0 - HALO_) && (hI <= h0 + TH_ + HALO_ - 2) &&
                           (wI >= w0 - HALO_) && (wI <= w0 + TW_ + HALO_ - 2);

        if (inbox) {
            const int ri0 = hc0 - (h0 - HALO_), ri1 = hc1 - (h0 - HALO_);
            const int rj0 = wc0 - (w0 - HALO_), rj1 = wc1 - (w0 - HALO_);
            const int r00 = ri0 * SW_ + rj0, r01 = ri0 * SW_ + rj1;
            const int r10 = ri1 * SW_ + rj0, r11 = ri1 * SW_ + rj1;

            const int bA = r00 * RECU_ + ((q ^ (r00 & 3)) << 2);
            const int bB = r01 * RECU_ + ((q ^ (r01 & 3)) << 2);
            const int bC = r10 * RECU_ + ((q ^ (r10 & 3)) << 2);
            const int bD = r11 * RECU_ + ((q ^ (r11 & 3)) << 2);

            // issue all 16 loads first (independent -> deep in-flight queue)
            const unsigned long long A0 = sm[bA],     A1 = sm[bA + 1];
            const unsigned long long A2 = sm[bA + 2], A3 = sm[bA + 3];
            const unsigned long long B0 = sm[bB],     B1 = sm[bB + 1];
            const unsigned long long B2 = sm[bB + 2], B3 = sm[bB + 3];
            const unsigned long long C0 = sm[bC],     C1 = sm[bC + 1];
            const unsigned long long C2 = sm[bC + 2], C3 = sm[bC + 3];
            const unsigned long long D0 = sm[bD],     D1 = sm[bD + 1];
            const unsigned long long D2 = sm[bD + 2], D3 = sm[bD + 3];

#define FMA8(Q0, Q1, Q2, Q3, WT)                                              \
            {                                                                 \
                unsigned u32;                                                 \
                u32 = (unsigned)(Q0);         acc[gr][0] = __hfma2(*(__half2*)&u32, (WT), acc[gr][0]); \
                u32 = (unsigned)((Q0) >> 32); acc[gr][1] = __hfma2(*(__half2*)&u32, (WT), acc[gr][1]); \
                u32 = (unsigned)(Q1);         acc[gr][2] = __hfma2(*(__half2*)&u32, (WT), acc[gr][2]); \
                u32 = (unsigned)((Q1) >> 32); acc[gr][3] = __hfma2(*(__half2*)&u32, (WT), acc[gr][3]); \
                u32 = (unsigned)(Q2);         acc[gr][4] = __hfma2(*(__half2*)&u32, (WT), acc[gr][4]); \
                u32 = (unsigned)((Q2) >> 32); acc[gr][5] = __hfma2(*(__half2*)&u32, (WT), acc[gr][5]); \
                u32 = (unsigned)(Q3);         acc[gr][6] = __hfma2(*(__half2*)&u32, (WT), acc[gr][6]); \
                u32 = (unsigned)((Q3) >> 32); acc[gr][7] = __hfma2(*(__half2*)&u32, (WT), acc[gr][7]); \
            }
            FMA8(A0, A1, A2, A3, W00)
            FMA8(B0, B1, B2, B3, W01)
            FMA8(C0, C1, C2, C3, W10)
            FMA8(D0, D1, D2, D3, W11)
#undef FMA8
        } else {
            // rare (P ~1e-4 per tap): direct global f32 loads at clamped coords
#define GCORNER(HC, WC, WT)                                                   \
            {                                                                 \
                const float* s = x + (size_t)((HC) * W_ + (WC)) * (G_ * C_) + g * C_ + chb; \
                _Pragma("unroll")                                             \
                for (int u = 0; u < 4; ++u) {                                 \
                    const float4 v = *(const float4*)(s + u * 4);             \
                    __half2 e0 = __floats2half2_rn(v.x, v.y);                 \
                    __half2 e1 = __floats2half2_rn(v.z, v.w);                 \
                    acc[gr][u*2]   = __hfma2(e0, (WT), acc[gr][u*2]);         \
                    acc[gr][u*2+1] = __hfma2(e1, (WT), acc[gr][u*2+1]);       \
                }                                                             \
            }
            GCORNER(hc0, wc0, W00) GCORNER(hc0, wc1, W01)
            GCORNER(hc1, wc0, W10) GCORNER(hc1, wc1, W11)
#undef GCORNER
        }
    }

    // fold 3 f16 groups in f32, store 16 channels (4x float4, coalesced)
    float* op = out + (size_t)pixg * C_ + chb;
#pragma unroll
    for (int a = 0; a < 8; a += 2) {
        const float2 s0 = __half22float2(acc[0][a]);
        const float2 t1 = __half22float2(acc[1][a]);
        const float2 t2 = __half22float2(acc[2][a]);
        const float2 s1 = __half22float2(acc[0][a + 1]);
        const float2 t3 = __half22float2(acc[1][a + 1]);
        const float2 t4 = __half22float2(acc[2][a + 1]);
        float4 o;
        o.x = s0.x + t1.x + t2.x;
        o.y = s0.y + t1.y + t2.y;
        o.z = s1.x + t3.x + t4.x;
        o.w = s1.y + t3.y + t4.y;
        *(float4*)(op + a * 2) = o;
    }
}

extern "C" void kernel_launch(void* const* d_in, const int* in_sizes, int n_in,
                              void* d_out, int out_size, void* d_ws, size_t ws_size,
                              hipStream_t stream) {
    const float* x      = (const float*)d_in[0];
    const float* offset = (const float*)d_in[1];
    const float* mask   = (const float*)d_in[2];
    float* out          = (float*)d_out;

    // 13x20 tiles x 8 groups = 2080 blocks of 256 threads
    dcn_lds_kernel<<<2080, 256, 0, stream>>>(x, offset, mask, out);
}

// Round 16
// 32.134 us; speedup vs baseline: 1.1589x; 1.1589x over previous
//
#include <hip/hip_runtime.h>
#include <hip/hip_fp16.h>

#define G_ 8
#define C_ 64
#define K_ 9
#define H_ 100
#define W_ 160
#define TW_ 8
#define TH_ 8
#define HALO_ 4
#define SW_ 16
#define SH_ 16
#define PLANE_ 273                 // uint4 per 8-ch plane: 16 rows * 17 cols + 1 pad
#define TAB_ (8 * PLANE_)          // 2184: tap-table base (uint4 index)
#define NLDS_ (TAB_ + 576)         // 2760 uint4 = 44160 B -> 3 blocks/CU

// One block = (group g, 8x8 pixel tile), 256 threads, 4 thr/pixel (16 ch:
// chunk q and q+4). x staged as 8 chunk-planes of 16-B records; bank-group
// (chunk+row+col)%8 -> near-uniform LDS banking. Tap table: 576 tasks compute
// softmax+bilinear weights ONCE per (pixel,tap) (4x VALU dedup vs R15) into
// 16-B LDS records. Phase B per tap: 1 broadcast table read + 8 ds_read_b128
// + 16 hfma2. Edge-clamped staging makes all zero-weight reads NaN-safe.
// Rare out-of-halo taps: flagged, exact global-f32 fixup (static indexing
// everywhere -- scratch-spill lesson from R11/R12).
__global__ __launch_bounds__(256, 4) void dcn_kernel(
    const float* __restrict__ x,      // [H,W,G*C] f32
    const float* __restrict__ offset, // [H,W,G*K*2]
    const float* __restrict__ mask,   // [H,W,G*K]
    float* __restrict__ out)          // [H,W,G*C]
{
    __shared__ uint4 sm[NLDS_];
    const int bid = (int)blockIdx.x;
    const int g   = bid & 7;          // group -> XCD round-robin
    const int t   = bid >> 3;         // 0..259 tile (13 rows x 20 cols)
    const int th  = t / 20, twc = t % 20;
    const int h0  = th * TH_, w0 = twc * TW_;
    const int tid = (int)threadIdx.x;

    // ---------- stage x tile+halo: 256 recs x 8 chunk-planes, edge-clamped ----
    // task: rec = task>>3 (8 lanes/rec -> 256 B coalesced global read), c = task&7
#pragma unroll
    for (int it = 0; it < 8; ++it) {
        const int task = it * 256 + tid;
        const int rec  = task >> 3;
        const int c    = task & 7;
        const int i = rec >> 4, j = rec & 15;
        const int hs = min(max(h0 - HALO_ + i, 0), H_ - 1);
        const int ws = min(max(w0 - HALO_ + j, 0), W_ - 1);
        const float* src = x + (size_t)(hs * W_ + ws) * (G_ * C_) + g * C_ + c * 8;
        const float4 A = *(const float4*)src;
        const float4 B = *(const float4*)(src + 4);
        __half2 p0 = __floats2half2_rn(A.x, A.y);
        __half2 p1 = __floats2half2_rn(A.z, A.w);
        __half2 p2 = __floats2half2_rn(B.x, B.y);
        __half2 p3 = __floats2half2_rn(B.z, B.w);
        uint4 v;
        v.x = *(unsigned*)&p0; v.y = *(unsigned*)&p1;
        v.z = *(unsigned*)&p2; v.w = *(unsigned*)&p3;
        sm[c * PLANE_ + i * 17 + j] = v;
    }

    // ---------- tap table: 576 tasks = 64 px x 9 taps, one task each ----------
    for (int task = tid; task < 576; task += 256) {
        const int px = task / 9;             // compiler magic-mul
        const int k  = task - px * 9;
        const int hh = h0 + (px >> 3), ww = w0 + (px & 7);
        uint4 r; r.x = 0u; r.y = 0u; r.z = 0u; r.w = 0u;
        if (hh < H_) {
            const int pixg = (hh * W_ + ww) * G_ + g;
            const float* mptr = mask + (size_t)pixg * K_;
            float mmax = -1e30f;
#pragma unroll
            for (int kk = 0; kk < K_; ++kk) mmax = fmaxf(mmax, mptr[kk]);
            float msum = 0.f;
#pragma unroll
            for (int kk = 0; kk < K_; ++kk) msum += __expf(mptr[kk] - mmax);
            const float m = __expf(mptr[k] - mmax) / msum;   // runtime k: global ptr only

            const float2 o2 = *(const float2*)(offset + (size_t)pixg * (2 * K_) + 2 * k);
            const float lh = (float)(hh + k / 3 - 1) + o2.x;
            const float lw = (float)(ww + k % 3 - 1) + o2.y;
            const float fh0 = floorf(lh), fw0 = floorf(lw);
            const float ft = lh - fh0, gt = lw - fw0;
            const int hI = (int)fh0, wI = (int)fw0;

            const float wh0 = (hI >= 0  && hI < H_    ) ? (1.f - ft) * m : 0.f;
            const float wh1 = (hI >= -1 && hI < H_ - 1) ? ft * m         : 0.f;
            const float cw0 = (wI >= 0  && wI < W_    ) ? (1.f - gt)     : 0.f;
            const float cw1 = (wI >= -1 && wI < W_ - 1) ? gt             : 0.f;
            __half2 wa = __floats2half2_rn(wh0 * cw0, wh0 * cw1);
            __half2 wb = __floats2half2_rn(wh1 * cw0, wh1 * cw1);

            const int hc0 = min(max(hI,     0), H_ - 1);
            const int hc1 = min(max(hI + 1, 0), H_ - 1);
            const int wc0 = min(max(wI,     0), W_ - 1);
            const int wc1 = min(max(wI + 1, 0), W_ - 1);

            const bool inbox = (hI >= h0 - HALO_) && (hI <= h0 + TH_ + HALO_ - 2) &&
                               (wI >= w0 - HALO_) && (wI <= w0 + TW_ + HALO_ - 2);
            if (inbox) {
                const int ri0 = hc0 - (h0 - HALO_);
                const int rj0 = wc0 - (w0 - HALO_);
                r.x = *(unsigned*)&wa;
                r.y = *(unsigned*)&wb;
                r.z = (unsigned)ri0 | ((unsigned)rj0 << 8)
                    | ((unsigned)(wc1 - wc0) << 16) | ((unsigned)(hc1 - hc0) << 17);
            } else {
                // zero weights, safe clamped in-box indices, OOB flag
                const int ri0 = min(max(hc0 - (h0 - HALO_), 0), SH_ - 1);
                const int rj0 = min(max(wc0 - (w0 - HALO_), 0), SW_ - 1);
                r.z = (unsigned)ri0 | ((unsigned)rj0 << 8) | 0x80000000u;
            }
        }
        sm[TAB_ + task] = r;
    }
    __syncthreads();

    // ---------- phase B: table-driven gather ----------
    const int px = tid >> 2;
    const int q  = tid & 3;
    const int hh = h0 + (px >> 3), ww = w0 + (px & 7);
    if (hh >= H_) return;
    const int pixg = (hh * W_ + ww) * G_ + g;
    const int pb0 = q * PLANE_;
    const int pb1 = (q + 4) * PLANE_;

    // prefetch all 9 tap records (broadcast reads, static names)
    const uint4 t0 = sm[TAB_ + px * 9 + 0];
    const uint4 t1 = sm[TAB_ + px * 9 + 1];
    const uint4 t2 = sm[TAB_ + px * 9 + 2];
    const uint4 t3 = sm[TAB_ + px * 9 + 3];
    const uint4 t4 = sm[TAB_ + px * 9 + 4];
    const uint4 t5 = sm[TAB_ + px * 9 + 5];
    const uint4 t6 = sm[TAB_ + px * 9 + 6];
    const uint4 t7 = sm[TAB_ + px * 9 + 7];
    const uint4 t8 = sm[TAB_ + px * 9 + 8];

    __half2 acc[3][8];
#pragma unroll
    for (int gr = 0; gr < 3; ++gr)
#pragma unroll
        for (int u = 0; u < 8; ++u) acc[gr][u] = __half2(__half(0.f), __half(0.f));

#define FMA4(V, WD, GR, OFF)                                                  \
    {                                                                         \
        const __half2 wt_ = *(const __half2*)&(WD);                           \
        acc[GR][(OFF)+0] = __hfma2(*(const __half2*)&(V).x, wt_, acc[GR][(OFF)+0]); \
        acc[GR][(OFF)+1] = __hfma2(*(const __half2*)&(V).y, wt_, acc[GR][(OFF)+1]); \
        acc[GR][(OFF)+2] = __hfma2(*(const __half2*)&(V).z, wt_, acc[GR][(OFF)+2]); \
        acc[GR][(OFF)+3] = __hfma2(*(const __half2*)&(V).w, wt_, acc[GR][(OFF)+3]); \
    }

#define GC(GR, HC, WC, WF)                                                    \
    {                                                                         \
        const __half2 wt_ = __float2half2_rn(WF);                             \
        const float* s_ = x + (size_t)((HC) * W_ + (WC)) * (G_ * C_) + g * C_ + q * 8; \
        const float4 v0 = *(const float4*)s_;                                 \
        const float4 v1 = *(const float4*)(s_ + 4);                           \
        const float4 v2 = *(const float4*)(s_ + 32);                          \
        const float4 v3 = *(const float4*)(s_ + 36);                          \
        __half2 e0 = __floats2half2_rn(v0.x, v0.y), e1 = __floats2half2_rn(v0.z, v0.w); \
        __half2 e2 = __floats2half2_rn(v1.x, v1.y), e3 = __floats2half2_rn(v1.z, v1.w); \
        __half2 e4 = __floats2half2_rn(v2.x, v2.y), e5 = __floats2half2_rn(v2.z, v2.w); \
        __half2 e6 = __floats2half2_rn(v3.x, v3.y), e7 = __floats2half2_rn(v3.z, v3.w); \
        acc[GR][0] = __hfma2(e0, wt_, acc[GR][0]);                            \
        acc[GR][1] = __hfma2(e1, wt_, acc[GR][1]);                            \
        acc[GR][2] = __hfma2(e2, wt_, acc[GR][2]);                            \
        acc[GR][3] = __hfma2(e3, wt_, acc[GR][3]);                            \
        acc[GR][4] = __hfma2(e4, wt_, acc[GR][4]);                            \
        acc[GR][5] = __hfma2(e5, wt_, acc[GR][5]);                            \
        acc[GR][6] = __hfma2(e6, wt_, acc[GR][6]);                            \
        acc[GR][7] = __hfma2(e7, wt_, acc[GR][7]);                            \
    }

#define SLOWTAP(KK)                                                           \
    {                                                                         \
        const float* mptr_ = mask + (size_t)pixg * K_;                        \
        float mmax_ = -1e30f;                                                 \
        _Pragma("unroll")                                                     \
        for (int kk = 0; kk < K_; ++kk) mmax_ = fmaxf(mmax_, mptr_[kk]);      \
        float msum_ = 0.f;                                                    \
        _Pragma("unroll")                                                     \
        for (int kk = 0; kk < K_; ++kk) msum_ += __expf(mptr_[kk] - mmax_);   \
        const float m_ = __expf(mptr_[KK] - mmax_) / msum_;                   \
        const float2 o2_ = *(const float2*)(offset + (size_t)pixg * (2 * K_) + 2 * (KK)); \
        const float lh_ = (float)(hh + (KK) / 3 - 1) + o2_.x;                 \
        const float lw_ = (float)(ww + (KK) % 3 - 1) + o2_.y;                 \
        const float fh_ = floorf(lh_), fw_ = floorf(lw_);                     \
        const float ft_ = lh_ - fh_, gt_ = lw_ - fw_;                         \
        const int hI_ = (int)fh_, wI_ = (int)fw_;                             \
        const float wh0_ = (hI_ >= 0  && hI_ < H_    ) ? (1.f - ft_) * m_ : 0.f; \
        const float wh1_ = (hI_ >= -1 && hI_ < H_ - 1) ? ft_ * m_         : 0.f; \
        const float cw0_ = (wI_ >= 0  && wI_ < W_    ) ? (1.f - gt_)     : 0.f; \
        const float cw1_ = (wI_ >= -1 && wI_ < W_ - 1) ? gt_             : 0.f; \
        const int hc0_ = min(max(hI_,     0), H_ - 1);                        \
        const int hc1_ = min(max(hI_ + 1, 0), H_ - 1);                        \
        const int wc0_ = min(max(wI_,     0), W_ - 1);                        \
        const int wc1_ = min(max(wI_ + 1, 0), W_ - 1);                        \
        GC((KK) / 3, hc0_, wc0_, wh0_ * cw0_)                                 \
        GC((KK) / 3, hc0_, wc1_, wh0_ * cw1_)                                 \
        GC((KK) / 3, hc1_, wc0_, wh1_ * cw0_)                                 \
        GC((KK) / 3, hc1_, wc1_, wh1_ * cw1_)                                 \
    }

#define TAP(KK, R)                                                            \
    {                                                                         \
        const int ri0_ = (int)((R).z & 0xffu);                                \
        const int rj0_ = (int)(((R).z >> 8) & 0xffu);                         \
        const int dc_  = (int)(((R).z >> 16) & 1u);                           \
        const int dr17_ = (((R).z >> 17) & 1u) ? 17 : 0;                      \
        const int i00_ = ri0_ * 17 + rj0_;                                    \
        const int i01_ = i00_ + dc_;                                          \
        const int i10_ = i00_ + dr17_;                                        \
        const int i11_ = i10_ + dc_;                                          \
        const unsigned W00d = __builtin_amdgcn_perm((R).x, (R).x, 0x01000100u); \
        const unsigned W01d = __builtin_amdgcn_perm((R).x, (R).x, 0x03020302u); \
        const unsigned W10d = __builtin_amdgcn_perm((R).y, (R).y, 0x01000100u); \
        const unsigned W11d = __builtin_amdgcn_perm((R).y, (R).y, 0x03020302u); \
        const uint4 A0 = sm[pb0 + i00_], A1 = sm[pb1 + i00_];                 \
        const uint4 B0 = sm[pb0 + i01_], B1 = sm[pb1 + i01_];                 \
        const uint4 C0 = sm[pb0 + i10_], C1 = sm[pb1 + i10_];                 \
        const uint4 D0 = sm[pb0 + i11_], D1 = sm[pb1 + i11_];                 \
        FMA4(A0, W00d, (KK) / 3, 0) FMA4(A1, W00d, (KK) / 3, 4)               \
        FMA4(B0, W01d, (KK) / 3, 0) FMA4(B1, W01d, (KK) / 3, 4)               \
        FMA4(C0, W10d, (KK) / 3, 0) FMA4(C1, W10d, (KK) / 3, 4)               \
        FMA4(D0, W11d, (KK) / 3, 0) FMA4(D1, W11d, (KK) / 3, 4)               \
        if (__builtin_expect(((R).z >> 31) != 0u, 0)) { SLOWTAP(KK) }         \
    }

    TAP(0, t0) TAP(1, t1) TAP(2, t2)
    TAP(3, t3) TAP(4, t4) TAP(5, t5)
    TAP(6, t6) TAP(7, t7) TAP(8, t8)

#undef TAP
#undef SLOWTAP
#undef GC
#undef FMA4

    // fold 3 f16 groups in f32; thread writes chunks q (ch q*8..) and q+4 (+32)
    float* op = out + (size_t)pixg * C_ + q * 8;
#pragma unroll
    for (int half = 0; half < 2; ++half) {
        const int ob = half * 4;            // acc offset 0 or 4
        const float2 s0 = __half22float2(acc[0][ob + 0]);
        const float2 a0 = __half22float2(acc[1][ob + 0]);
        const float2 b0 = __half22float2(acc[2][ob + 0]);
        const float2 s1 = __half22float2(acc[0][ob + 1]);
        const float2 a1 = __half22float2(acc[1][ob + 1]);
        const float2 b1 = __half22float2(acc[2][ob + 1]);
        const float2 s2 = __half22float2(acc[0][ob + 2]);
        const float2 a2 = __half22float2(acc[1][ob + 2]);
        const float2 b2 = __half22float2(acc[2][ob + 2]);
        const float2 s3 = __half22float2(acc[0][ob + 3]);
        const float2 a3 = __half22float2(acc[1][ob + 3]);
        const float2 b3 = __half22float2(acc[2][ob + 3]);
        float4 o1, o2;
        o1.x = s0.x + a0.x + b0.x;  o1.y = s0.y + a0.y + b0.y;
        o1.z = s1.x + a1.x + b1.x;  o1.w = s1.y + a1.y + b1.y;
        o2.x = s2.x + a2.x + b2.x;  o2.y = s2.y + a2.y + b2.y;
        o2.z = s3.x + a3.x + b3.x;  o2.w = s3.y + a3.y + b3.y;
        *(float4*)(op + half * 32)     = o1;
        *(float4*)(op + half * 32 + 4) = o2;
    }
}

extern "C" void kernel_launch(void* const* d_in, const int* in_sizes, int n_in,
                              void* d_out, int out_size, void* d_ws, size_t ws_size,
                              hipStream_t stream) {
    const float* x      = (const float*)d_in[0];
    const float* offset = (const float*)d_in[1];
    const float* mask   = (const float*)d_in[2];
    float* out          = (float*)d_out;

    // 13x20 tiles x 8 groups = 2080 blocks of 256 threads
    dcn_kernel<<<2080, 256, 0, stream>>>(x, offset, mask, out);
}

// Round 18
// 30.302 us; speedup vs baseline: 1.2289x; 1.0604x over previous
//
#include <hip/hip_runtime.h>
#include <hip/hip_fp16.h>

#define G_ 8
#define C_ 64
#define K_ 9
#define H_ 100
#define W_ 160
#define TW_ 8
#define TH_ 8
#define HALO_ 4
#define SW_ 16
#define SH_ 16
#define PLANE_ 273                 // uint4 per 8-ch plane: 16*17 + 1 (273 % 8 == 1)
#define TAB_ (8 * PLANE_)          // 2184: tap-table base (uint4 index)
#define NLDS_ (TAB_ + 576)         // 2760 uint4 = 44160 B -> 3 blocks/CU

// R16 + 8 threads/pixel (one 8-channel plane each): 512-thread blocks, same
// 8x8 tile and 44 KB LDS -> 3 blocks/CU but 24 waves/CU (was 12). Tap table
// still computed once per (pixel,tap). Banking: addr(u4) = c*273 + i*17 + j,
// 273=1, 17=1 (mod 8) -> bank-group (c+i+j)%8; each pixel octet sweeps all 8
// groups -> wave's 256 dword accesses spread exactly 8/bank. Edge-clamped
// staging; exact global-f32 fixup for rare out-of-halo taps; all register
// arrays statically indexed (R11/R12 scratch-spill lesson).
// (R17 fix: corner locals renamed vA_..vD_ -- C_ collided with #define C_.)
__global__ __launch_bounds__(512, 6) void dcn_kernel(
    const float* __restrict__ x,      // [H,W,G*C] f32
    const float* __restrict__ offset, // [H,W,G*K*2]
    const float* __restrict__ mask,   // [H,W,G*K]
    float* __restrict__ out)          // [H,W,G*C]
{
    __shared__ uint4 sm[NLDS_];
    const int bid = (int)blockIdx.x;
    const int g   = bid & 7;          // group -> XCD round-robin
    const int t   = bid >> 3;         // 0..259 tile (13 rows x 20 cols)
    const int th  = t / 20, twc = t % 20;
    const int h0  = th * TH_, w0 = twc * TW_;
    const int tid = (int)threadIdx.x;

    // ---------- stage x tile+halo: 256 recs x 8 chunk-planes, edge-clamped ----
    // 2048 tasks = 4 x 512; 8 lanes/rec -> 256 B coalesced global reads
#pragma unroll
    for (int it = 0; it < 4; ++it) {
        const int task = it * 512 + tid;
        const int rec  = task >> 3;
        const int c    = task & 7;
        const int i = rec >> 4, j = rec & 15;
        const int hs = min(max(h0 - HALO_ + i, 0), H_ - 1);
        const int ws = min(max(w0 - HALO_ + j, 0), W_ - 1);
        const float* src = x + (size_t)(hs * W_ + ws) * (G_ * C_) + g * C_ + c * 8;
        const float4 A = *(const float4*)src;
        const float4 B = *(const float4*)(src + 4);
        __half2 p0 = __floats2half2_rn(A.x, A.y);
        __half2 p1 = __floats2half2_rn(A.z, A.w);
        __half2 p2 = __floats2half2_rn(B.x, B.y);
        __half2 p3 = __floats2half2_rn(B.z, B.w);
        uint4 v;
        v.x = *(unsigned*)&p0; v.y = *(unsigned*)&p1;
        v.z = *(unsigned*)&p2; v.w = *(unsigned*)&p3;
        sm[c * PLANE_ + i * 17 + j] = v;
    }

    // ---------- tap table: 576 tasks = 64 px x 9 taps, one task each ----------
    for (int task = tid; task < 576; task += 512) {
        const int px = task / 9;
        const int k  = task - px * 9;
        const int hh = h0 + (px >> 3), ww = w0 + (px & 7);
        uint4 r; r.x = 0u; r.y = 0u; r.z = 0u; r.w = 0u;
        if (hh < H_) {
            const int pixg = (hh * W_ + ww) * G_ + g;
            const float* mptr = mask + (size_t)pixg * K_;
            float mmax = -1e30f;
#pragma unroll
            for (int kk = 0; kk < K_; ++kk) mmax = fmaxf(mmax, mptr[kk]);
            float msum = 0.f;
#pragma unroll
            for (int kk = 0; kk < K_; ++kk) msum += __expf(mptr[kk] - mmax);
            const float m = __expf(mptr[k] - mmax) / msum;   // runtime k: global ptr only

            const float2 o2 = *(const float2*)(offset + (size_t)pixg * (2 * K_) + 2 * k);
            const float lh = (float)(hh + k / 3 - 1) + o2.x;
            const float lw = (float)(ww + k % 3 - 1) + o2.y;
            const float fh0 = floorf(lh), fw0 = floorf(lw);
            const float ft = lh - fh0, gt = lw - fw0;
            const int hI = (int)fh0, wI = (int)fw0;

            const float wh0 = (hI >= 0  && hI < H_    ) ? (1.f - ft) * m : 0.f;
            const float wh1 = (hI >= -1 && hI < H_ - 1) ? ft * m         : 0.f;
            const float cw0 = (wI >= 0  && wI < W_    ) ? (1.f - gt)     : 0.f;
            const float cw1 = (wI >= -1 && wI < W_ - 1) ? gt             : 0.f;
            __half2 wa = __floats2half2_rn(wh0 * cw0, wh0 * cw1);
            __half2 wb = __floats2half2_rn(wh1 * cw0, wh1 * cw1);

            const int hc0 = min(max(hI,     0), H_ - 1);
            const int hc1 = min(max(hI + 1, 0), H_ - 1);
            const int wc0 = min(max(wI,     0), W_ - 1);
            const int wc1 = min(max(wI + 1, 0), W_ - 1);

            const bool inbox = (hI >= h0 - HALO_) && (hI <= h0 + TH_ + HALO_ - 2) &&
                               (wI >= w0 - HALO_) && (wI <= w0 + TW_ + HALO_ - 2);
            if (inbox) {
                const int ri0 = hc0 - (h0 - HALO_);
                const int rj0 = wc0 - (w0 - HALO_);
                r.x = *(unsigned*)&wa;
                r.y = *(unsigned*)&wb;
                r.z = (unsigned)ri0 | ((unsigned)rj0 << 8)
                    | ((unsigned)(wc1 - wc0) << 16) | ((unsigned)(hc1 - hc0) << 17);
            } else {
                const int ri0 = min(max(hc0 - (h0 - HALO_), 0), SH_ - 1);
                const int rj0 = min(max(wc0 - (w0 - HALO_), 0), SW_ - 1);
                r.z = (unsigned)ri0 | ((unsigned)rj0 << 8) | 0x80000000u;
            }
        }
        sm[TAB_ + task] = r;
    }
    __syncthreads();

    // ---------- phase B: table-driven gather, 8 thr/pixel ----------
    const int px = tid >> 3;            // 0..63 pixel in tile
    const int c  = tid & 7;             // 8-channel chunk / plane
    const int hh = h0 + (px >> 3), ww = w0 + (px & 7);
    if (hh >= H_) return;
    const int pixg = (hh * W_ + ww) * G_ + g;
    const int pb = c * PLANE_;

    // prefetch all 9 tap records (broadcast reads, static names)
    const uint4 t0 = sm[TAB_ + px * 9 + 0];
    const uint4 t1 = sm[TAB_ + px * 9 + 1];
    const uint4 t2 = sm[TAB_ + px * 9 + 2];
    const uint4 t3 = sm[TAB_ + px * 9 + 3];
    const uint4 t4 = sm[TAB_ + px * 9 + 4];
    const uint4 t5 = sm[TAB_ + px * 9 + 5];
    const uint4 t6 = sm[TAB_ + px * 9 + 6];
    const uint4 t7 = sm[TAB_ + px * 9 + 7];
    const uint4 t8 = sm[TAB_ + px * 9 + 8];

    __half2 acc[3][4];
#pragma unroll
    for (int gr = 0; gr < 3; ++gr)
#pragma unroll
        for (int u = 0; u < 4; ++u) acc[gr][u] = __half2(__half(0.f), __half(0.f));

#define FMA4(V, WD, GR)                                                       \
    {                                                                         \
        const __half2 wt_ = *(const __half2*)&(WD);                           \
        acc[GR][0] = __hfma2(*(const __half2*)&(V).x, wt_, acc[GR][0]);       \
        acc[GR][1] = __hfma2(*(const __half2*)&(V).y, wt_, acc[GR][1]);       \
        acc[GR][2] = __hfma2(*(const __half2*)&(V).z, wt_, acc[GR][2]);       \
        acc[GR][3] = __hfma2(*(const __half2*)&(V).w, wt_, acc[GR][3]);       \
    }

#define GC(GR, HC, WC, WF)                                                    \
    {                                                                         \
        const __half2 wt_ = __float2half2_rn(WF);                             \
        const float* s_ = x + (size_t)((HC) * W_ + (WC)) * (G_ * C_) + g * C_ + c * 8; \
        const float4 v0 = *(const float4*)s_;                                 \
        const float4 v1 = *(const float4*)(s_ + 4);                           \
        __half2 e0 = __floats2half2_rn(v0.x, v0.y), e1 = __floats2half2_rn(v0.z, v0.w); \
        __half2 e2 = __floats2half2_rn(v1.x, v1.y), e3 = __floats2half2_rn(v1.z, v1.w); \
        acc[GR][0] = __hfma2(e0, wt_, acc[GR][0]);                            \
        acc[GR][1] = __hfma2(e1, wt_, acc[GR][1]);                            \
        acc[GR][2] = __hfma2(e2, wt_, acc[GR][2]);                            \
        acc[GR][3] = __hfma2(e3, wt_, acc[GR][3]);                            \
    }

#define SLOWTAP(KK)                                                           \
    {                                                                         \
        const float* mptr_ = mask + (size_t)pixg * K_;                        \
        float mmax_ = -1e30f;                                                 \
        _Pragma("unroll")                                                     \
        for (int kk = 0; kk < K_; ++kk) mmax_ = fmaxf(mmax_, mptr_[kk]);      \
        float msum_ = 0.f;                                                    \
        _Pragma("unroll")                                                     \
        for (int kk = 0; kk < K_; ++kk) msum_ += __expf(mptr_[kk] - mmax_);   \
        const float m_ = __expf(mptr_[KK] - mmax_) / msum_;                   \
        const float2 o2_ = *(const float2*)(offset + (size_t)pixg * (2 * K_) + 2 * (KK)); \
        const float lh_ = (float)(hh + (KK) / 3 - 1) + o2_.x;                 \
        const float lw_ = (float)(ww + (KK) % 3 - 1) + o2_.y;                 \
        const float fh_ = floorf(lh_), fw_ = floorf(lw_);                     \
        const float ft_ = lh_ - fh_, gt_ = lw_ - fw_;                         \
        const int hI_ = (int)fh_, wI_ = (int)fw_;                             \
        const float wh0_ = (hI_ >= 0  && hI_ < H_    ) ? (1.f - ft_) * m_ : 0.f; \
        const float wh1_ = (hI_ >= -1 && hI_ < H_ - 1) ? ft_ * m_         : 0.f; \
        const float cw0_ = (wI_ >= 0  && wI_ < W_    ) ? (1.f - gt_)     : 0.f; \
        const float cw1_ = (wI_ >= -1 && wI_ < W_ - 1) ? gt_             : 0.f; \
        const int hc0_ = min(max(hI_,     0), H_ - 1);                        \
        const int hc1_ = min(max(hI_ + 1, 0), H_ - 1);                        \
        const int wc0_ = min(max(wI_,     0), W_ - 1);                        \
        const int wc1_ = min(max(wI_ + 1, 0), W_ - 1);                        \
        GC((KK) / 3, hc0_, wc0_, wh0_ * cw0_)                                 \
        GC((KK) / 3, hc0_, wc1_, wh0_ * cw1_)                                 \
        GC((KK) / 3, hc1_, wc0_, wh1_ * cw0_)                                 \
        GC((KK) / 3, hc1_, wc1_, wh1_ * cw1_)                                 \
    }

#define TAP(KK, R)                                                            \
    {                                                                         \
        const int ri0_ = (int)((R).z & 0xffu);                                \
        const int rj0_ = (int)(((R).z >> 8) & 0xffu);                         \
        const int dc_  = (int)(((R).z >> 16) & 1u);                           \
        const int dr17_ = (((R).z >> 17) & 1u) ? 17 : 0;                      \
        const int i00_ = pb + ri0_ * 17 + rj0_;                               \
        const int i01_ = i00_ + dc_;                                          \
        const int i10_ = i00_ + dr17_;                                        \
        const int i11_ = i10_ + dc_;                                          \
        const unsigned W00d = __builtin_amdgcn_perm((R).x, (R).x, 0x01000100u); \
        const unsigned W01d = __builtin_amdgcn_perm((R).x, (R).x, 0x03020302u); \
        const unsigned W10d = __builtin_amdgcn_perm((R).y, (R).y, 0x01000100u); \
        const unsigned W11d = __builtin_amdgcn_perm((R).y, (R).y, 0x03020302u); \
        const uint4 vA_ = sm[i00_];                                           \
        const uint4 vB_ = sm[i01_];                                           \
        const uint4 vC_ = sm[i10_];                                           \
        const uint4 vD_ = sm[i11_];                                           \
        FMA4(vA_, W00d, (KK) / 3)                                             \
        FMA4(vB_, W01d, (KK) / 3)                                             \
        FMA4(vC_, W10d, (KK) / 3)                                             \
        FMA4(vD_, W11d, (KK) / 3)                                             \
        if (__builtin_expect(((R).z >> 31) != 0u, 0)) { SLOWTAP(KK) }         \
    }

    TAP(0, t0) TAP(1, t1) TAP(2, t2)
    TAP(3, t3) TAP(4, t4) TAP(5, t5)
    TAP(6, t6) TAP(7, t7) TAP(8, t8)

#undef TAP
#undef SLOWTAP
#undef GC
#undef FMA4

    // fold 3 f16 groups in f32; thread writes its 8 channels (2x float4)
    float* op = out + (size_t)pixg * C_ + c * 8;
    {
        const float2 s0 = __half22float2(acc[0][0]);
        const float2 a0 = __half22float2(acc[1][0]);
        const float2 b0 = __half22float2(acc[2][0]);
        const float2 s1 = __half22float2(acc[0][1]);
        const float2 a1 = __half22float2(acc[1][1]);
        const float2 b1 = __half22float2(acc[2][1]);
        const float2 s2 = __half22float2(acc[0][2]);
        const float2 a2 = __half22float2(acc[1][2]);
        const float2 b2 = __half22float2(acc[2][2]);
        const float2 s3 = __half22float2(acc[0][3]);
        const float2 a3 = __half22float2(acc[1][3]);
        const float2 b3 = __half22float2(acc[2][3]);
        float4 o1, o2;
        o1.x = s0.x + a0.x + b0.x;  o1.y = s0.y + a0.y + b0.y;
        o1.z = s1.x + a1.x + b1.x;  o1.w = s1.y + a1.y + b1.y;
        o2.x = s2.x + a2.x + b2.x;  o2.y = s2.y + a2.y + b2.y;
        o2.z = s3.x + a3.x + b3.x;  o2.w = s3.y + a3.y + b3.y;
        *(float4*)op       = o1;
        *(float4*)(op + 4) = o2;
    }
}

extern "C" void kernel_launch(void* const* d_in, const int* in_sizes, int n_in,
                              void* d_out, int out_size, void* d_ws, size_t ws_size,
                              hipStream_t stream) {
    const float* x      = (const float*)d_in[0];
    const float* offset = (const float*)d_in[1];
    const float* mask   = (const float*)d_in[2];
    float* out          = (float*)d_out;

    // 13x20 tiles x 8 groups = 2080 blocks of 512 threads
    dcn_kernel<<<2080, 512, 0, stream>>>(x, offset, mask, out);
}

// Round 19
// 29.808 us; speedup vs baseline: 1.2493x; 1.0166x over previous
//
#include <hip/hip_runtime.h>
#include <hip/hip_fp16.h>

#define G_ 8
#define C_ 64
#define K_ 9
#define H_ 100
#define W_ 160
#define TW_ 8
#define TH_ 8
#define HALO_ 4
#define SW_ 16
#define SH_ 16
#define PLANE_ 257                 // uint4 per 8-ch plane: 16x16 XOR-swizzled + 1 pad (257%8==1)
#define NXP_ (8 * PLANE_)          // 2056 uint4 = 32896 B

// R18 + 4 blocks/CU: XOR-swizzled 16x16 planes (PLANE=257 u4) + tap table
// packed as 3 u32 arrays (12 B/rec) -> LDS 39.8 KB < 40 KB -> 4 blocks/CU,
// 32 waves/CU (100% wave cap). launch_bounds(512,8) pins VGPR<=64; phase B
// loads tap records in-TAP (no 9-wide prefetch) to fit. Banking: plane addr
// u4 = c*257 + i*16 + (j^(i&7)); 257=1 mod 8 -> bank-group (c + j^s)%8,
// each pixel-octet sweeps all 8 groups. Edge-clamped staging; exact
// global-f32 fixup for rare out-of-halo taps; static indexing everywhere.
__global__ __launch_bounds__(512, 8) void dcn_kernel(
    const float* __restrict__ x,      // [H,W,G*C] f32
    const float* __restrict__ offset, // [H,W,G*K*2]
    const float* __restrict__ mask,   // [H,W,G*K]
    float* __restrict__ out)          // [H,W,G*C]
{
    __shared__ uint4 smx[NXP_];
    __shared__ unsigned smw0[576], smw1[576], smidx[576];

    const int bid = (int)blockIdx.x;
    const int g   = bid & 7;          // group -> XCD round-robin (L2 partition)
    const int t   = bid >> 3;         // 0..259 tile (13 rows x 20 cols)
    const int th  = t / 20, twc = t % 20;
    const int h0  = th * TH_, w0 = twc * TW_;
    const int tid = (int)threadIdx.x;

    // ---------- stage x tile+halo: 256 recs x 8 chunk-planes, edge-clamped ----
    // 2048 tasks = 4 x 512; 8 lanes/rec -> 256 B coalesced global reads
#pragma unroll
    for (int it = 0; it < 4; ++it) {
        const int task = it * 512 + tid;
        const int rec  = task >> 3;
        const int c    = task & 7;
        const int i = rec >> 4, j = rec & 15;
        const int hs = min(max(h0 - HALO_ + i, 0), H_ - 1);
        const int ws = min(max(w0 - HALO_ + j, 0), W_ - 1);
        const float* src = x + (size_t)(hs * W_ + ws) * (G_ * C_) + g * C_ + c * 8;
        const float4 A = *(const float4*)src;
        const float4 B = *(const float4*)(src + 4);
        __half2 p0 = __floats2half2_rn(A.x, A.y);
        __half2 p1 = __floats2half2_rn(A.z, A.w);
        __half2 p2 = __floats2half2_rn(B.x, B.y);
        __half2 p3 = __floats2half2_rn(B.z, B.w);
        uint4 v;
        v.x = *(unsigned*)&p0; v.y = *(unsigned*)&p1;
        v.z = *(unsigned*)&p2; v.w = *(unsigned*)&p3;
        smx[c * PLANE_ + i * 16 + (j ^ (i & 7))] = v;
    }

    // ---------- tap table: 576 tasks = 64 px x 9 taps, one task each ----------
    for (int task = tid; task < 576; task += 512) {
        const int px = task / 9;
        const int k  = task - px * 9;
        const int hh = h0 + (px >> 3), ww = w0 + (px & 7);
        unsigned rw0 = 0u, rw1 = 0u, ridx = 0u;
        if (hh < H_) {
            const int pixg = (hh * W_ + ww) * G_ + g;
            const float* mptr = mask + (size_t)pixg * K_;
            float mmax = -1e30f;
#pragma unroll
            for (int kk = 0; kk < K_; ++kk) mmax = fmaxf(mmax, mptr[kk]);
            float msum = 0.f;
#pragma unroll
            for (int kk = 0; kk < K_; ++kk) msum += __expf(mptr[kk] - mmax);
            const float m = __expf(mptr[k] - mmax) / msum;   // runtime k: global ptr only

            const float2 o2 = *(const float2*)(offset + (size_t)pixg * (2 * K_) + 2 * k);
            const float lh = (float)(hh + k / 3 - 1) + o2.x;
            const float lw = (float)(ww + k % 3 - 1) + o2.y;
            const float fh0 = floorf(lh), fw0 = floorf(lw);
            const float ft = lh - fh0, gt = lw - fw0;
            const int hI = (int)fh0, wI = (int)fw0;

            const float wh0 = (hI >= 0  && hI < H_    ) ? (1.f - ft) * m : 0.f;
            const float wh1 = (hI >= -1 && hI < H_ - 1) ? ft * m         : 0.f;
            const float cw0 = (wI >= 0  && wI < W_    ) ? (1.f - gt)     : 0.f;
            const float cw1 = (wI >= -1 && wI < W_ - 1) ? gt             : 0.f;
            __half2 wa = __floats2half2_rn(wh0 * cw0, wh0 * cw1);
            __half2 wb = __floats2half2_rn(wh1 * cw0, wh1 * cw1);

            const int hc0 = min(max(hI,     0), H_ - 1);
            const int hc1 = min(max(hI + 1, 0), H_ - 1);
            const int wc0 = min(max(wI,     0), W_ - 1);
            const int wc1 = min(max(wI + 1, 0), W_ - 1);

            const bool inbox = (hI >= h0 - HALO_) && (hI <= h0 + TH_ + HALO_ - 2) &&
                               (wI >= w0 - HALO_) && (wI <= w0 + TW_ + HALO_ - 2);
            if (inbox) {
                const int ri0 = hc0 - (h0 - HALO_);
                const int rj0 = wc0 - (w0 - HALO_);
                rw0 = *(unsigned*)&wa;
                rw1 = *(unsigned*)&wb;
                ridx = (unsigned)ri0 | ((unsigned)rj0 << 8)
                     | ((unsigned)(wc1 - wc0) << 16) | ((unsigned)(hc1 - hc0) << 17);
            } else {
                const int ri0 = min(max(hc0 - (h0 - HALO_), 0), SH_ - 1);
                const int rj0 = min(max(wc0 - (w0 - HALO_), 0), SW_ - 1);
                ridx = (unsigned)ri0 | ((unsigned)rj0 << 8) | 0x80000000u;
            }
        }
        smw0[task] = rw0;
        smw1[task] = rw1;
        smidx[task] = ridx;
    }
    __syncthreads();

    // ---------- phase B: table-driven gather, 8 thr/pixel ----------
    const int px = tid >> 3;            // 0..63 pixel in tile
    const int c  = tid & 7;             // 8-channel chunk / plane
    const int hh = h0 + (px >> 3), ww = w0 + (px & 7);
    if (hh >= H_) return;
    const int pixg = (hh * W_ + ww) * G_ + g;
    const int pb = c * PLANE_;
    const int tb = px * 9;

    __half2 acc[3][4];
#pragma unroll
    for (int gr = 0; gr < 3; ++gr)
#pragma unroll
        for (int u = 0; u < 4; ++u) acc[gr][u] = __half2(__half(0.f), __half(0.f));

#define FMA4(V, WD, GR)                                                       \
    {                                                                         \
        const __half2 wt_ = *(const __half2*)&(WD);                           \
        acc[GR][0] = __hfma2(*(const __half2*)&(V).x, wt_, acc[GR][0]);       \
        acc[GR][1] = __hfma2(*(const __half2*)&(V).y, wt_, acc[GR][1]);       \
        acc[GR][2] = __hfma2(*(const __half2*)&(V).z, wt_, acc[GR][2]);       \
        acc[GR][3] = __hfma2(*(const __half2*)&(V).w, wt_, acc[GR][3]);       \
    }

#define GC(GR, HC, WC, WF)                                                    \
    {                                                                         \
        const __half2 wt_ = __float2half2_rn(WF);                             \
        const float* s_ = x + (size_t)((HC) * W_ + (WC)) * (G_ * C_) + g * C_ + c * 8; \
        const float4 v0 = *(const float4*)s_;                                 \
        const float4 v1 = *(const float4*)(s_ + 4);                           \
        __half2 e0 = __floats2half2_rn(v0.x, v0.y), e1 = __floats2half2_rn(v0.z, v0.w); \
        __half2 e2 = __floats2half2_rn(v1.x, v1.y), e3 = __floats2half2_rn(v1.z, v1.w); \
        acc[GR][0] = __hfma2(e0, wt_, acc[GR][0]);                            \
        acc[GR][1] = __hfma2(e1, wt_, acc[GR][1]);                            \
        acc[GR][2] = __hfma2(e2, wt_, acc[GR][2]);                            \
        acc[GR][3] = __hfma2(e3, wt_, acc[GR][3]);                            \
    }

#define SLOWTAP(KK)                                                           \
    {                                                                         \
        const float* mptr_ = mask + (size_t)pixg * K_;                        \
        float mmax_ = -1e30f;                                                 \
        _Pragma("unroll")                                                     \
        for (int kk = 0; kk < K_; ++kk) mmax_ = fmaxf(mmax_, mptr_[kk]);      \
        float msum_ = 0.f;                                                    \
        _Pragma("unroll")                                                     \
        for (int kk = 0; kk < K_; ++kk) msum_ += __expf(mptr_[kk] - mmax_);   \
        const float m_ = __expf(mptr_[KK] - mmax_) / msum_;                   \
        const float2 o2_ = *(const float2*)(offset + (size_t)pixg * (2 * K_) + 2 * (KK)); \
        const float lh_ = (float)(hh + (KK) / 3 - 1) + o2_.x;                 \
        const float lw_ = (float)(ww + (KK) % 3 - 1) + o2_.y;                 \
        const float fh_ = floorf(lh_), fw_ = floorf(lw_);                     \
        const float ft_ = lh_ - fh_, gt_ = lw_ - fw_;                         \
        const int hI_ = (int)fh_, wI_ = (int)fw_;                             \
        const float wh0_ = (hI_ >= 0  && hI_ < H_    ) ? (1.f - ft_) * m_ : 0.f; \
        const float wh1_ = (hI_ >= -1 && hI_ < H_ - 1) ? ft_ * m_         : 0.f; \
        const float cw0_ = (wI_ >= 0  && wI_ < W_    ) ? (1.f - gt_)     : 0.f; \
        const float cw1_ = (wI_ >= -1 && wI_ < W_ - 1) ? gt_             : 0.f; \
        const int hc0_ = min(max(hI_,     0), H_ - 1);                        \
        const int hc1_ = min(max(hI_ + 1, 0), H_ - 1);                        \
        const int wc0_ = min(max(wI_,     0), W_ - 1);                        \
        const int wc1_ = min(max(wI_ + 1, 0), W_ - 1);                        \
        GC((KK) / 3, hc0_, wc0_, wh0_ * cw0_)                                 \
        GC((KK) / 3, hc0_, wc1_, wh0_ * cw1_)                                 \
        GC((KK) / 3, hc1_, wc0_, wh1_ * cw0_)                                 \
        GC((KK) / 3, hc1_, wc1_, wh1_ * cw1_)                                 \
    }

#define TAP(KK)                                                               \
    {                                                                         \
        const unsigned ridx_ = smidx[tb + (KK)];                              \
        const unsigned rw0_  = smw0[tb + (KK)];                               \
        const unsigned rw1_  = smw1[tb + (KK)];                               \
        const int ri0_ = (int)(ridx_ & 0xffu);                                \
        const int rj0_ = (int)((ridx_ >> 8) & 0xffu);                         \
        const int dc_  = (int)((ridx_ >> 16) & 1u);                           \
        const int dr_  = (int)((ridx_ >> 17) & 1u);                           \
        const int ri1_ = ri0_ + dr_;                                          \
        const int rj1_ = rj0_ + dc_;                                          \
        const int s0_  = ri0_ & 7, s1_ = ri1_ & 7;                            \
        const int row0_ = pb + ri0_ * 16, row1_ = pb + ri1_ * 16;             \
        const int i00_ = row0_ + (rj0_ ^ s0_);                                \
        const int i01_ = row0_ + (rj1_ ^ s0_);                                \
        const int i10_ = row1_ + (rj0_ ^ s1_);                                \
        const int i11_ = row1_ + (rj1_ ^ s1_);                                \
        const unsigned W00d = __builtin_amdgcn_perm(rw0_, rw0_, 0x01000100u); \
        const unsigned W01d = __builtin_amdgcn_perm(rw0_, rw0_, 0x03020302u); \
        const unsigned W10d = __builtin_amdgcn_perm(rw1_, rw1_, 0x01000100u); \
        const unsigned W11d = __builtin_amdgcn_perm(rw1_, rw1_, 0x03020302u); \
        const uint4 vA_ = smx[i00_];                                          \
        const uint4 vB_ = smx[i01_];                                          \
        const uint4 vC_ = smx[i10_];                                          \
        const uint4 vD_ = smx[i11_];                                          \
        FMA4(vA_, W00d, (KK) / 3)                                             \
        FMA4(vB_, W01d, (KK) / 3)                                             \
        FMA4(vC_, W10d, (KK) / 3)                                             \
        FMA4(vD_, W11d, (KK) / 3)                                             \
        if (__builtin_expect((ridx_ >> 31) != 0u, 0)) { SLOWTAP(KK) }         \
    }

    TAP(0) TAP(1) TAP(2)
    TAP(3) TAP(4) TAP(5)
    TAP(6) TAP(7) TAP(8)

#undef TAP
#undef SLOWTAP
#undef GC
#undef FMA4

    // fold 3 f16 groups in f32; thread writes its 8 channels (2x float4)
    float* op = out + (size_t)pixg * C_ + c * 8;
    {
        const float2 s0 = __half22float2(acc[0][0]);
        const float2 a0 = __half22float2(acc[1][0]);
        const float2 b0 = __half22float2(acc[2][0]);
        const float2 s1 = __half22float2(acc[0][1]);
        const float2 a1 = __half22float2(acc[1][1]);
        const float2 b1 = __half22float2(acc[2][1]);
        const float2 s2 = __half22float2(acc[0][2]);
        const float2 a2 = __half22float2(acc[1][2]);
        const float2 b2 = __half22float2(acc[2][2]);
        const float2 s3 = __half22float2(acc[0][3]);
        const float2 a3 = __half22float2(acc[1][3]);
        const float2 b3 = __half22float2(acc[2][3]);
        float4 o1, o2;
        o1.x = s0.x + a0.x + b0.x;  o1.y = s0.y + a0.y + b0.y;
        o1.z = s1.x + a1.x + b1.x;  o1.w = s1.y + a1.y + b1.y;
        o2.x = s2.x + a2.x + b2.x;  o2.y = s2.y + a2.y + b2.y;
        o2.z = s3.x + a3.x + b3.x;  o2.w = s3.y + a3.y + b3.y;
        *(float4*)op       = o1;
        *(float4*)(op + 4) = o2;
    }
}

extern "C" void kernel_launch(void* const* d_in, const int* in_sizes, int n_in,
                              void* d_out, int out_size, void* d_ws, size_t ws_size,
                              hipStream_t stream) {
    const float* x      = (const float*)d_in[0];
    const float* offset = (const float*)d_in[1];
    const float* mask   = (const float*)d_in[2];
    float* out          = (float*)d_out;

    // 13x20 tiles x 8 groups = 2080 blocks of 512 threads
    dcn_kernel<<<2080, 512, 0, stream>>>(x, offset, mask, out);
}

// Round 20
// 28.758 us; speedup vs baseline: 1.2949x; 1.0365x over previous
//
#include <hip/hip_runtime.h>
#include <hip/hip_fp16.h>

#define G_ 8
#define C_ 64
#define K_ 9
#define H_ 100
#define W_ 160
#define TW_ 8
#define TH_ 8
#define HALO_ 4
#define SW_ 16
#define SH_ 16
#define NXP_ 2048                  // 256 recs x 8 chunks, uint4 each = 32768 B

// R19 simplified: x staged as plain [rec][c] row-major uint4 (addr_u4 =
// rec*8+c). For a pixel octet (c=0..7) a ds_read_b128 starts at bank 4c ->
// banks 0,4,...,28: provably conflict-free, zero swizzle VALU. Tap table =
// uint2 weights + u32 idx (2 DS broadcasts/tap). LDS 39.7 KB -> 4 blocks/CU,
// 32 waves/CU. Edge-clamped staging; exact global-f32 fixup for rare
// out-of-halo taps; static indexing everywhere (R11/R12 spill lesson).
__global__ __launch_bounds__(512, 8) void dcn_kernel(
    const float* __restrict__ x,      // [H,W,G*C] f32
    const float* __restrict__ offset, // [H,W,G*K*2]
    const float* __restrict__ mask,   // [H,W,G*K]
    float* __restrict__ out)          // [H,W,G*C]
{
    __shared__ uint4 smx[NXP_];
    __shared__ uint2 smwp[576];
    __shared__ unsigned smidx[576];

    const int bid = (int)blockIdx.x;
    const int g   = bid & 7;          // group -> XCD round-robin (L2 partition)
    const int t   = bid >> 3;         // 0..259 tile (13 rows x 20 cols)
    const int th  = t / 20, twc = t % 20;
    const int h0  = th * TH_, w0 = twc * TW_;
    const int tid = (int)threadIdx.x;

    // ---------- stage x tile+halo: 256 recs x 8 chunks, edge-clamped ----------
    // 2048 tasks = 4 x 512; 8 lanes/rec -> 256 B coalesced global reads;
    // LDS write address = linear in task.
#pragma unroll
    for (int it = 0; it < 4; ++it) {
        const int task = it * 512 + tid;
        const int rec  = task >> 3;
        const int c    = task & 7;
        const int i = rec >> 4, j = rec & 15;
        const int hs = min(max(h0 - HALO_ + i, 0), H_ - 1);
        const int ws = min(max(w0 - HALO_ + j, 0), W_ - 1);
        const float* src = x + (size_t)(hs * W_ + ws) * (G_ * C_) + g * C_ + c * 8;
        const float4 A = *(const float4*)src;
        const float4 B = *(const float4*)(src + 4);
        __half2 p0 = __floats2half2_rn(A.x, A.y);
        __half2 p1 = __floats2half2_rn(A.z, A.w);
        __half2 p2 = __floats2half2_rn(B.x, B.y);
        __half2 p3 = __floats2half2_rn(B.z, B.w);
        uint4 v;
        v.x = *(unsigned*)&p0; v.y = *(unsigned*)&p1;
        v.z = *(unsigned*)&p2; v.w = *(unsigned*)&p3;
        smx[task] = v;
    }

    // ---------- tap table: 576 tasks = 64 px x 9 taps, one task each ----------
    for (int task = tid; task < 576; task += 512) {
        const int px = task / 9;
        const int k  = task - px * 9;
        const int hh = h0 + (px >> 3), ww = w0 + (px & 7);
        unsigned rw0 = 0u, rw1 = 0u, ridx = 0u;
        if (hh < H_) {
            const int pixg = (hh * W_ + ww) * G_ + g;
            const float* mptr = mask + (size_t)pixg * K_;
            float mmax = -1e30f;
#pragma unroll
            for (int kk = 0; kk < K_; ++kk) mmax = fmaxf(mmax, mptr[kk]);
            float msum = 0.f;
#pragma unroll
            for (int kk = 0; kk < K_; ++kk) msum += __expf(mptr[kk] - mmax);
            const float m = __expf(mptr[k] - mmax) / msum;   // runtime k: global ptr only

            const float2 o2 = *(const float2*)(offset + (size_t)pixg * (2 * K_) + 2 * k);
            const float lh = (float)(hh + k / 3 - 1) + o2.x;
            const float lw = (float)(ww + k % 3 - 1) + o2.y;
            const float fh0 = floorf(lh), fw0 = floorf(lw);
            const float ft = lh - fh0, gt = lw - fw0;
            const int hI = (int)fh0, wI = (int)fw0;

            const float wh0 = (hI >= 0  && hI < H_    ) ? (1.f - ft) * m : 0.f;
            const float wh1 = (hI >= -1 && hI < H_ - 1) ? ft * m         : 0.f;
            const float cw0 = (wI >= 0  && wI < W_    ) ? (1.f - gt)     : 0.f;
            const float cw1 = (wI >= -1 && wI < W_ - 1) ? gt             : 0.f;
            __half2 wa = __floats2half2_rn(wh0 * cw0, wh0 * cw1);
            __half2 wb = __floats2half2_rn(wh1 * cw0, wh1 * cw1);

            const int hc0 = min(max(hI,     0), H_ - 1);
            const int hc1 = min(max(hI + 1, 0), H_ - 1);
            const int wc0 = min(max(wI,     0), W_ - 1);
            const int wc1 = min(max(wI + 1, 0), W_ - 1);

            const bool inbox = (hI >= h0 - HALO_) && (hI <= h0 + TH_ + HALO_ - 2) &&
                               (wI >= w0 - HALO_) && (wI <= w0 + TW_ + HALO_ - 2);
            if (inbox) {
                const int ri0 = hc0 - (h0 - HALO_);
                const int rj0 = wc0 - (w0 - HALO_);
                rw0 = *(unsigned*)&wa;
                rw1 = *(unsigned*)&wb;
                ridx = (unsigned)ri0 | ((unsigned)rj0 << 8)
                     | ((unsigned)(wc1 - wc0) << 16) | ((unsigned)(hc1 - hc0) << 17);
            } else {
                const int ri0 = min(max(hc0 - (h0 - HALO_), 0), SH_ - 1);
                const int rj0 = min(max(wc0 - (w0 - HALO_), 0), SW_ - 1);
                ridx = (unsigned)ri0 | ((unsigned)rj0 << 8) | 0x80000000u;
            }
        }
        smwp[task] = make_uint2(rw0, rw1);
        smidx[task] = ridx;
    }
    __syncthreads();

    // ---------- phase B: table-driven gather, 8 thr/pixel ----------
    const int px = tid >> 3;            // 0..63 pixel in tile
    const int c  = tid & 7;             // 8-channel chunk
    const int hh = h0 + (px >> 3), ww = w0 + (px & 7);
    if (hh >= H_) return;
    const int pixg = (hh * W_ + ww) * G_ + g;
    const int tb = px * 9;

    __half2 acc[3][4];
#pragma unroll
    for (int gr = 0; gr < 3; ++gr)
#pragma unroll
        for (int u = 0; u < 4; ++u) acc[gr][u] = __half2(__half(0.f), __half(0.f));

#define FMA4(V, WD, GR)                                                       \
    {                                                                         \
        const __half2 wt_ = *(const __half2*)&(WD);                           \
        acc[GR][0] = __hfma2(*(const __half2*)&(V).x, wt_, acc[GR][0]);       \
        acc[GR][1] = __hfma2(*(const __half2*)&(V).y, wt_, acc[GR][1]);       \
        acc[GR][2] = __hfma2(*(const __half2*)&(V).z, wt_, acc[GR][2]);       \
        acc[GR][3] = __hfma2(*(const __half2*)&(V).w, wt_, acc[GR][3]);       \
    }

#define GC(GR, HC, WC, WF)                                                    \
    {                                                                         \
        const __half2 wt_ = __float2half2_rn(WF);                             \
        const float* s_ = x + (size_t)((HC) * W_ + (WC)) * (G_ * C_) + g * C_ + c * 8; \
        const float4 v0 = *(const float4*)s_;                                 \
        const float4 v1 = *(const float4*)(s_ + 4);                           \
        __half2 e0 = __floats2half2_rn(v0.x, v0.y), e1 = __floats2half2_rn(v0.z, v0.w); \
        __half2 e2 = __floats2half2_rn(v1.x, v1.y), e3 = __floats2half2_rn(v1.z, v1.w); \
        acc[GR][0] = __hfma2(e0, wt_, acc[GR][0]);                            \
        acc[GR][1] = __hfma2(e1, wt_, acc[GR][1]);                            \
        acc[GR][2] = __hfma2(e2, wt_, acc[GR][2]);                            \
        acc[GR][3] = __hfma2(e3, wt_, acc[GR][3]);                            \
    }

#define SLOWTAP(KK)                                                           \
    {                                                                         \
        const float* mptr_ = mask + (size_t)pixg * K_;                        \
        float mmax_ = -1e30f;                                                 \
        _Pragma("unroll")                                                     \
        for (int kk = 0; kk < K_; ++kk) mmax_ = fmaxf(mmax_, mptr_[kk]);      \
        float msum_ = 0.f;                                                    \
        _Pragma("unroll")                                                     \
        for (int kk = 0; kk < K_; ++kk) msum_ += __expf(mptr_[kk] - mmax_);   \
        const float m_ = __expf(mptr_[KK] - mmax_) / msum_;                   \
        const float2 o2_ = *(const float2*)(offset + (size_t)pixg * (2 * K_) + 2 * (KK)); \
        const float lh_ = (float)(hh + (KK) / 3 - 1) + o2_.x;                 \
        const float lw_ = (float)(ww + (KK) % 3 - 1) + o2_.y;                 \
        const float fh_ = floorf(lh_), fw_ = floorf(lw_);                     \
        const float ft_ = lh_ - fh_, gt_ = lw_ - fw_;                         \
        const int hI_ = (int)fh_, wI_ = (int)fw_;                             \
        const float wh0_ = (hI_ >= 0  && hI_ < H_    ) ? (1.f - ft_) * m_ : 0.f; \
        const float wh1_ = (hI_ >= -1 && hI_ < H_ - 1) ? ft_ * m_         : 0.f; \
        const float cw0_ = (wI_ >= 0  && wI_ < W_    ) ? (1.f - gt_)     : 0.f; \
        const float cw1_ = (wI_ >= -1 && wI_ < W_ - 1) ? gt_             : 0.f; \
        const int hc0_ = min(max(hI_,     0), H_ - 1);                        \
        const int hc1_ = min(max(hI_ + 1, 0), H_ - 1);                        \
        const int wc0_ = min(max(wI_,     0), W_ - 1);                        \
        const int wc1_ = min(max(wI_ + 1, 0), W_ - 1);                        \
        GC((KK) / 3, hc0_, wc0_, wh0_ * cw0_)                                 \
        GC((KK) / 3, hc0_, wc1_, wh0_ * cw1_)                                 \
        GC((KK) / 3, hc1_, wc0_, wh1_ * cw0_)                                 \
        GC((KK) / 3, hc1_, wc1_, wh1_ * cw1_)                                 \
    }

#define TAP(KK)                                                               \
    {                                                                         \
        const unsigned ridx_ = smidx[tb + (KK)];                              \
        const uint2    rwp_  = smwp[tb + (KK)];                               \
        const int ri0_ = (int)(ridx_ & 0xffu);                                \
        const int rj0_ = (int)((ridx_ >> 8) & 0xffu);                         \
        const int dc8_  = (int)((ridx_ >> 16) & 1u) << 3;                     \
        const int dr128_ = (int)((ridx_ >> 17) & 1u) << 7;                    \
        const int i00_ = ri0_ * 128 + rj0_ * 8 + c;                           \
        const int i01_ = i00_ + dc8_;                                         \
        const int i10_ = i00_ + dr128_;                                       \
        const int i11_ = i10_ + dc8_;                                         \
        const unsigned W00d = __builtin_amdgcn_perm(rwp_.x, rwp_.x, 0x01000100u); \
        const unsigned W01d = __builtin_amdgcn_perm(rwp_.x, rwp_.x, 0x03020302u); \
        const unsigned W10d = __builtin_amdgcn_perm(rwp_.y, rwp_.y, 0x01000100u); \
        const unsigned W11d = __builtin_amdgcn_perm(rwp_.y, rwp_.y, 0x03020302u); \
        const uint4 vA_ = smx[i00_];                                          \
        const uint4 vB_ = smx[i01_];                                          \
        const uint4 vC_ = smx[i10_];                                          \
        const uint4 vD_ = smx[i11_];                                          \
        FMA4(vA_, W00d, (KK) / 3)                                             \
        FMA4(vB_, W01d, (KK) / 3)                                             \
        FMA4(vC_, W10d, (KK) / 3)                                             \
        FMA4(vD_, W11d, (KK) / 3)                                             \
        if (__builtin_expect((ridx_ >> 31) != 0u, 0)) { SLOWTAP(KK) }         \
    }

    TAP(0) TAP(1) TAP(2)
    TAP(3) TAP(4) TAP(5)
    TAP(6) TAP(7) TAP(8)

#undef TAP
#undef SLOWTAP
#undef GC
#undef FMA4

    // fold 3 f16 groups in f32; thread writes its 8 channels (2x float4)
    float* op = out + (size_t)pixg * C_ + c * 8;
    {
        const float2 s0 = __half22float2(acc[0][0]);
        const float2 a0 = __half22float2(acc[1][0]);
        const float2 b0 = __half22float2(acc[2][0]);
        const float2 s1 = __half22float2(acc[0][1]);
        const float2 a1 = __half22float2(acc[1][1]);
        const float2 b1 = __half22float2(acc[2][1]);
        const float2 s2 = __half22float2(acc[0][2]);
        const float2 a2 = __half22float2(acc[1][2]);
        const float2 b2 = __half22float2(acc[2][2]);
        const float2 s3 = __half22float2(acc[0][3]);
        const float2 a3 = __half22float2(acc[1][3]);
        const float2 b3 = __half22float2(acc[2][3]);
        float4 o1, o2;
        o1.x = s0.x + a0.x + b0.x;  o1.y = s0.y + a0.y + b0.y;
        o1.z = s1.x + a1.x + b1.x;  o1.w = s1.y + a1.y + b1.y;
        o2.x = s2.x + a2.x + b2.x;  o2.y = s2.y + a2.y + b2.y;
        o2.z = s3.x + a3.x + b3.x;  o2.w = s3.y + a3.y + b3.y;
        *(float4*)op       = o1;
        *(float4*)(op + 4) = o2;
    }
}

extern "C" void kernel_launch(void* const* d_in, const int* in_sizes, int n_in,
                              void* d_out, int out_size, void* d_ws, size_t ws_size,
                              hipStream_t stream) {
    const float* x      = (const float*)d_in[0];
    const float* offset = (const float*)d_in[1];
    const float* mask   = (const float*)d_in[2];
    float* out          = (float*)d_out;

    // 13x20 tiles x 8 groups = 2080 blocks of 512 threads
    dcn_kernel<<<2080, 512, 0, stream>>>(x, offset, mask, out);
}

// Round 21
// 28.377 us; speedup vs baseline: 1.3123x; 1.0134x over previous
//
#include <hip/hip_runtime.h>
#include <hip/hip_fp16.h>

#define G_ 8
#define C_ 64
#define K_ 9
#define H_ 100
#define W_ 160
#define TW_ 8
#define TH_ 8
#define HALO_ 4
#define SW_ 16
#define SH_ 16
#define NXP_ 2048                  // 256 recs x 8 chunks, uint4 each = 32768 B

// R20 + per-tap VALU trim: (1) tap table stores the ready-made corner base
// (ri0*128+rj0*8, 11 bits) and add-values dc8 (0/8) / dr128 (0/128) -- TAP
// does 3 adds instead of extract+shift+mad; (2) weight splats via
// __half2half2(__low2half/__high2half) so clang can fold them into
// v_pk_fma_f16 op_sel (no v_perm). x staged as plain [rec][c] row-major
// uint4: pixel octet (c=0..7) ds_read_b128 starts at bank 4c -> conflict-
// free. LDS 39.7 KB -> 4 blocks/CU, 32 waves/CU. Edge-clamped staging;
// exact global-f32 fixup for rare out-of-halo taps; static indexing
// everywhere (R11/R12 spill lesson).
__global__ __launch_bounds__(512, 8) void dcn_kernel(
    const float* __restrict__ x,      // [H,W,G*C] f32
    const float* __restrict__ offset, // [H,W,G*K*2]
    const float* __restrict__ mask,   // [H,W,G*K]
    float* __restrict__ out)          // [H,W,G*C]
{
    __shared__ uint4 smx[NXP_];
    __shared__ uint2 smwp[576];
    __shared__ unsigned smidx[576];

    const int bid = (int)blockIdx.x;
    const int g   = bid & 7;          // group -> XCD round-robin (L2 partition)
    const int t   = bid >> 3;         // 0..259 tile (13 rows x 20 cols)
    const int th  = t / 20, twc = t % 20;
    const int h0  = th * TH_, w0 = twc * TW_;
    const int tid = (int)threadIdx.x;

    // ---------- stage x tile+halo: 256 recs x 8 chunks, edge-clamped ----------
    // 2048 tasks = 4 x 512; 8 lanes/rec -> 256 B coalesced global reads;
    // LDS write address = linear in task.
#pragma unroll
    for (int it = 0; it < 4; ++it) {
        const int task = it * 512 + tid;
        const int rec  = task >> 3;
        const int c    = task & 7;
        const int i = rec >> 4, j = rec & 15;
        const int hs = min(max(h0 - HALO_ + i, 0), H_ - 1);
        const int ws = min(max(w0 - HALO_ + j, 0), W_ - 1);
        const float* src = x + (size_t)(hs * W_ + ws) * (G_ * C_) + g * C_ + c * 8;
        const float4 A = *(const float4*)src;
        const float4 B = *(const float4*)(src + 4);
        __half2 p0 = __floats2half2_rn(A.x, A.y);
        __half2 p1 = __floats2half2_rn(A.z, A.w);
        __half2 p2 = __floats2half2_rn(B.x, B.y);
        __half2 p3 = __floats2half2_rn(B.z, B.w);
        uint4 v;
        v.x = *(unsigned*)&p0; v.y = *(unsigned*)&p1;
        v.z = *(unsigned*)&p2; v.w = *(unsigned*)&p3;
        smx[task] = v;
    }

    // ---------- tap table: 576 tasks = 64 px x 9 taps, one task each ----------
    for (int task = tid; task < 576; task += 512) {
        const int px = task / 9;
        const int k  = task - px * 9;
        const int hh = h0 + (px >> 3), ww = w0 + (px & 7);
        unsigned rw0 = 0u, rw1 = 0u, ridx = 0u;
        if (hh < H_) {
            const int pixg = (hh * W_ + ww) * G_ + g;
            const float* mptr = mask + (size_t)pixg * K_;
            float mmax = -1e30f;
#pragma unroll
            for (int kk = 0; kk < K_; ++kk) mmax = fmaxf(mmax, mptr[kk]);
            float msum = 0.f;
#pragma unroll
            for (int kk = 0; kk < K_; ++kk) msum += __expf(mptr[kk] - mmax);
            const float m = __expf(mptr[k] - mmax) / msum;   // runtime k: global ptr only

            const float2 o2 = *(const float2*)(offset + (size_t)pixg * (2 * K_) + 2 * k);
            const float lh = (float)(hh + k / 3 - 1) + o2.x;
            const float lw = (float)(ww + k % 3 - 1) + o2.y;
            const float fh0 = floorf(lh), fw0 = floorf(lw);
            const float ft = lh - fh0, gt = lw - fw0;
            const int hI = (int)fh0, wI = (int)fw0;

            const float wh0 = (hI >= 0  && hI < H_    ) ? (1.f - ft) * m : 0.f;
            const float wh1 = (hI >= -1 && hI < H_ - 1) ? ft * m         : 0.f;
            const float cw0 = (wI >= 0  && wI < W_    ) ? (1.f - gt)     : 0.f;
            const float cw1 = (wI >= -1 && wI < W_ - 1) ? gt             : 0.f;
            __half2 wa = __floats2half2_rn(wh0 * cw0, wh0 * cw1);
            __half2 wb = __floats2half2_rn(wh1 * cw0, wh1 * cw1);

            const int hc0 = min(max(hI,     0), H_ - 1);
            const int hc1 = min(max(hI + 1, 0), H_ - 1);
            const int wc0 = min(max(wI,     0), W_ - 1);
            const int wc1 = min(max(wI + 1, 0), W_ - 1);

            const bool inbox = (hI >= h0 - HALO_) && (hI <= h0 + TH_ + HALO_ - 2) &&
                               (wI >= w0 - HALO_) && (wI <= w0 + TW_ + HALO_ - 2);
            if (inbox) {
                const int ri0 = hc0 - (h0 - HALO_);
                const int rj0 = wc0 - (w0 - HALO_);
                rw0 = *(unsigned*)&wa;
                rw1 = *(unsigned*)&wb;
                ridx = (unsigned)(ri0 * 128 + rj0 * 8)                 // base, 11 bits
                     | ((unsigned)((wc1 - wc0) << 3) << 11)            // dc8: 0 or 8
                     | ((unsigned)((hc1 - hc0) << 7) << 15);           // dr128: 0 or 128
            } else {
                const int ri0 = min(max(hc0 - (h0 - HALO_), 0), SH_ - 1);
                const int rj0 = min(max(wc0 - (w0 - HALO_), 0), SW_ - 1);
                ridx = (unsigned)(ri0 * 128 + rj0 * 8) | 0x80000000u;
            }
        }
        smwp[task] = make_uint2(rw0, rw1);
        smidx[task] = ridx;
    }
    __syncthreads();

    // ---------- phase B: table-driven gather, 8 thr/pixel ----------
    const int px = tid >> 3;            // 0..63 pixel in tile
    const int c  = tid & 7;             // 8-channel chunk
    const int hh = h0 + (px >> 3), ww = w0 + (px & 7);
    if (hh >= H_) return;
    const int pixg = (hh * W_ + ww) * G_ + g;
    const int tb = px * 9;

    __half2 acc[3][4];
#pragma unroll
    for (int gr = 0; gr < 3; ++gr)
#pragma unroll
        for (int u = 0; u < 4; ++u) acc[gr][u] = __half2(__half(0.f), __half(0.f));

#define FMA4(V, WT, GR)                                                       \
    {                                                                         \
        acc[GR][0] = __hfma2(*(const __half2*)&(V).x, (WT), acc[GR][0]);      \
        acc[GR][1] = __hfma2(*(const __half2*)&(V).y, (WT), acc[GR][1]);      \
        acc[GR][2] = __hfma2(*(const __half2*)&(V).z, (WT), acc[GR][2]);      \
        acc[GR][3] = __hfma2(*(const __half2*)&(V).w, (WT), acc[GR][3]);      \
    }

#define GC(GR, HC, WC, WF)                                                    \
    {                                                                         \
        const __half2 wt_ = __float2half2_rn(WF);                             \
        const float* s_ = x + (size_t)((HC) * W_ + (WC)) * (G_ * C_) + g * C_ + c * 8; \
        const float4 v0 = *(const float4*)s_;                                 \
        const float4 v1 = *(const float4*)(s_ + 4);                           \
        __half2 e0 = __floats2half2_rn(v0.x, v0.y), e1 = __floats2half2_rn(v0.z, v0.w); \
        __half2 e2 = __floats2half2_rn(v1.x, v1.y), e3 = __floats2half2_rn(v1.z, v1.w); \
        acc[GR][0] = __hfma2(e0, wt_, acc[GR][0]);                            \
        acc[GR][1] = __hfma2(e1, wt_, acc[GR][1]);                            \
        acc[GR][2] = __hfma2(e2, wt_, acc[GR][2]);                            \
        acc[GR][3] = __hfma2(e3, wt_, acc[GR][3]);                            \
    }

#define SLOWTAP(KK)                                                           \
    {                                                                         \
        const float* mptr_ = mask + (size_t)pixg * K_;                        \
        float mmax_ = -1e30f;                                                 \
        _Pragma("unroll")                                                     \
        for (int kk = 0; kk < K_; ++kk) mmax_ = fmaxf(mmax_, mptr_[kk]);      \
        float msum_ = 0.f;                                                    \
        _Pragma("unroll")                                                     \
        for (int kk = 0; kk < K_; ++kk) msum_ += __expf(mptr_[kk] - mmax_);   \
        const float m_ = __expf(mptr_[KK] - mmax_) / msum_;                   \
        const float2 o2_ = *(const float2*)(offset + (size_t)pixg * (2 * K_) + 2 * (KK)); \
        const float lh_ = (float)(hh + (KK) / 3 - 1) + o2_.x;                 \
        const float lw_ = (float)(ww + (KK) % 3 - 1) + o2_.y;                 \
        const float fh_ = floorf(lh_), fw_ = floorf(lw_);                     \
        const float ft_ = lh_ - fh_, gt_ = lw_ - fw_;                         \
        const int hI_ = (int)fh_, wI_ = (int)fw_;                             \
        const float wh0_ = (hI_ >= 0  && hI_ < H_    ) ? (1.f - ft_) * m_ : 0.f; \
        const float wh1_ = (hI_ >= -1 && hI_ < H_ - 1) ? ft_ * m_         : 0.f; \
        const float cw0_ = (wI_ >= 0  && wI_ < W_    ) ? (1.f - gt_)     : 0.f; \
        const float cw1_ = (wI_ >= -1 && wI_ < W_ - 1) ? gt_             : 0.f; \
        const int hc0_ = min(max(hI_,     0), H_ - 1);                        \
        const int hc1_ = min(max(hI_ + 1, 0), H_ - 1);                        \
        const int wc0_ = min(max(wI_,     0), W_ - 1);                        \
        const int wc1_ = min(max(wI_ + 1, 0), W_ - 1);                        \
        GC((KK) / 3, hc0_, wc0_, wh0_ * cw0_)                                 \
        GC((KK) / 3, hc0_, wc1_, wh0_ * cw1_)                                 \
        GC((KK) / 3, hc1_, wc0_, wh1_ * cw0_)                                 \
        GC((KK) / 3, hc1_, wc1_, wh1_ * cw1_)                                 \
    }

#define TAP(KK)                                                               \
    {                                                                         \
        const unsigned ridx_ = smidx[tb + (KK)];                              \
        const uint2    rwp_  = smwp[tb + (KK)];                               \
        const int i00_ = (int)(ridx_ & 0x7ffu) + c;                           \
        const int dc8_   = (int)((ridx_ >> 11) & 0xfu);                       \
        const int dr128_ = (int)((ridx_ >> 15) & 0xffu);                      \
        const int i01_ = i00_ + dc8_;                                         \
        const int i10_ = i00_ + dr128_;                                       \
        const int i11_ = i10_ + dc8_;                                         \
        const __half2 wa_ = *(const __half2*)&rwp_.x;                         \
        const __half2 wb_ = *(const __half2*)&rwp_.y;                         \
        const __half2 W00 = __half2half2(__low2half(wa_));                    \
        const __half2 W01 = __half2half2(__high2half(wa_));                   \
        const __half2 W10 = __half2half2(__low2half(wb_));                    \
        const __half2 W11 = __half2half2(__high2half(wb_));                   \
        const uint4 vA_ = smx[i00_];                                          \
        const uint4 vB_ = smx[i01_];                                          \
        const uint4 vC_ = smx[i10_];                                          \
        const uint4 vD_ = smx[i11_];                                          \
        FMA4(vA_, W00, (KK) / 3)                                              \
        FMA4(vB_, W01, (KK) / 3)                                              \
        FMA4(vC_, W10, (KK) / 3)                                              \
        FMA4(vD_, W11, (KK) / 3)                                              \
        if (__builtin_expect((ridx_ >> 31) != 0u, 0)) { SLOWTAP(KK) }         \
    }

    TAP(0) TAP(1) TAP(2)
    TAP(3) TAP(4) TAP(5)
    TAP(6) TAP(7) TAP(8)

#undef TAP
#undef SLOWTAP
#undef GC
#undef FMA4

    // fold 3 f16 groups in f32; thread writes its 8 channels (2x float4)
    float* op = out + (size_t)pixg * C_ + c * 8;
    {
        const float2 s0 = __half22float2(acc[0][0]);
        const float2 a0 = __half22float2(acc[1][0]);
        const float2 b0 = __half22float2(acc[2][0]);
        const float2 s1 = __half22float2(acc[0][1]);
        const float2 a1 = __half22float2(acc[1][1]);
        const float2 b1 = __half22float2(acc[2][1]);
        const float2 s2 = __half22float2(acc[0][2]);
        const float2 a2 = __half22float2(acc[1][2]);
        const float2 b2 = __half22float2(acc[2][2]);
        const float2 s3 = __half22float2(acc[0][3]);
        const float2 a3 = __half22float2(acc[1][3]);
        const float2 b3 = __half22float2(acc[2][3]);
        float4 o1, o2;
        o1.x = s0.x + a0.x + b0.x;  o1.y = s0.y + a0.y + b0.y;
        o1.z = s1.x + a1.x + b1.x;  o1.w = s1.y + a1.y + b1.y;
        o2.x = s2.x + a2.x + b2.x;  o2.y = s2.y + a2.y + b2.y;
        o2.z = s3.x + a3.x + b3.x;  o2.w = s3.y + a3.y + b3.y;
        *(float4*)op       = o1;
        *(float4*)(op + 4) = o2;
    }
}

extern "C" void kernel_launch(void* const* d_in, const int* in_sizes, int n_in,
                              void* d_out, int out_size, void* d_ws, size_t ws_size,
                              hipStream_t stream) {
    const float* x      = (const float*)d_in[0];
    const float* offset = (const float*)d_in[1];
    const float* mask   = (const float*)d_in[2];
    float* out          = (float*)d_out;

    // 13x20 tiles x 8 groups = 2080 blocks of 512 threads
    dcn_kernel<<<2080, 512, 0, stream>>>(x, offset, mask, out);
}

// Round 22
// 27.364 us; speedup vs baseline: 1.3609x; 1.0370x over previous
//
#include <hip/hip_runtime.h>
#include <hip/hip_fp16.h>

#define G_ 8
#define C_ 64
#define K_ 9
#define H_ 100
#define W_ 160
#define TW_ 8
#define TH_ 8
#define HALO_ 4
#define SW_ 16
#define SH_ 16
#define NXP_ 2048                  // 256 recs x 8 chunks, uint4 each = 32768 B

// R21 + cheap fallback: phase A stores the tap weights for ALL taps (OOB
// included) and, for OOB taps, the packed clamped GLOBAL coords
// (hc0:7b | wc0:8b | dh | dw | flag). TAP is a real if/else: fast = 4 LDS
// corner reads; slow = 4 global 32-B corner loads with the same table
// weights -- no softmax/offset recompute (was ~400+ cyc, now ~80). x staged
// as plain [rec][c] row-major uint4 (pixel octet -> banks 4c: conflict-
// free). LDS 39.7 KB -> 4 blocks/CU, 32 waves/CU. Static indexing
// everywhere (R11/R12 spill lesson).
__global__ __launch_bounds__(512, 8) void dcn_kernel(
    const float* __restrict__ x,      // [H,W,G*C] f32
    const float* __restrict__ offset, // [H,W,G*K*2]
    const float* __restrict__ mask,   // [H,W,G*K]
    float* __restrict__ out)          // [H,W,G*C]
{
    __shared__ uint4 smx[NXP_];
    __shared__ uint2 smwp[576];
    __shared__ unsigned smidx[576];

    const int bid = (int)blockIdx.x;
    const int g   = bid & 7;          // group -> XCD round-robin (L2 partition)
    const int t   = bid >> 3;         // 0..259 tile (13 rows x 20 cols)
    const int th  = t / 20, twc = t % 20;
    const int h0  = th * TH_, w0 = twc * TW_;
    const int tid = (int)threadIdx.x;

    // ---------- stage x tile+halo: 256 recs x 8 chunks, edge-clamped ----------
#pragma unroll
    for (int it = 0; it < 4; ++it) {
        const int task = it * 512 + tid;
        const int rec  = task >> 3;
        const int c    = task & 7;
        const int i = rec >> 4, j = rec & 15;
        const int hs = min(max(h0 - HALO_ + i, 0), H_ - 1);
        const int ws = min(max(w0 - HALO_ + j, 0), W_ - 1);
        const float* src = x + (size_t)(hs * W_ + ws) * (G_ * C_) + g * C_ + c * 8;
        const float4 A = *(const float4*)src;
        const float4 B = *(const float4*)(src + 4);
        __half2 p0 = __floats2half2_rn(A.x, A.y);
        __half2 p1 = __floats2half2_rn(A.z, A.w);
        __half2 p2 = __floats2half2_rn(B.x, B.y);
        __half2 p3 = __floats2half2_rn(B.z, B.w);
        uint4 v;
        v.x = *(unsigned*)&p0; v.y = *(unsigned*)&p1;
        v.z = *(unsigned*)&p2; v.w = *(unsigned*)&p3;
        smx[task] = v;
    }

    // ---------- tap table: 576 tasks = 64 px x 9 taps, one task each ----------
    for (int task = tid; task < 576; task += 512) {
        const int px = task / 9;
        const int k  = task - px * 9;
        const int hh = h0 + (px >> 3), ww = w0 + (px & 7);
        unsigned rw0 = 0u, rw1 = 0u, ridx = 0u;
        if (hh < H_) {
            const int pixg = (hh * W_ + ww) * G_ + g;
            const float* mptr = mask + (size_t)pixg * K_;
            float mmax = -1e30f;
#pragma unroll
            for (int kk = 0; kk < K_; ++kk) mmax = fmaxf(mmax, mptr[kk]);
            float msum = 0.f;
#pragma unroll
            for (int kk = 0; kk < K_; ++kk) msum += __expf(mptr[kk] - mmax);
            const float m = __expf(mptr[k] - mmax) / msum;   // runtime k: global ptr only

            const float2 o2 = *(const float2*)(offset + (size_t)pixg * (2 * K_) + 2 * k);
            const float lh = (float)(hh + k / 3 - 1) + o2.x;
            const float lw = (float)(ww + k % 3 - 1) + o2.y;
            const float fh0 = floorf(lh), fw0 = floorf(lw);
            const float ft = lh - fh0, gt = lw - fw0;
            const int hI = (int)fh0, wI = (int)fw0;

            const float wh0 = (hI >= 0  && hI < H_    ) ? (1.f - ft) * m : 0.f;
            const float wh1 = (hI >= -1 && hI < H_ - 1) ? ft * m         : 0.f;
            const float cw0 = (wI >= 0  && wI < W_    ) ? (1.f - gt)     : 0.f;
            const float cw1 = (wI >= -1 && wI < W_ - 1) ? gt             : 0.f;
            __half2 wa = __floats2half2_rn(wh0 * cw0, wh0 * cw1);
            __half2 wb = __floats2half2_rn(wh1 * cw0, wh1 * cw1);
            rw0 = *(unsigned*)&wa;
            rw1 = *(unsigned*)&wb;

            const int hc0 = min(max(hI,     0), H_ - 1);
            const int hc1 = min(max(hI + 1, 0), H_ - 1);
            const int wc0 = min(max(wI,     0), W_ - 1);
            const int wc1 = min(max(wI + 1, 0), W_ - 1);

            const bool inbox = (hI >= h0 - HALO_) && (hI <= h0 + TH_ + HALO_ - 2) &&
                               (wI >= w0 - HALO_) && (wI <= w0 + TW_ + HALO_ - 2);
            if (inbox) {
                const int ri0 = hc0 - (h0 - HALO_);
                const int rj0 = wc0 - (w0 - HALO_);
                ridx = (unsigned)(ri0 * 128 + rj0 * 8)                 // base, 11 bits
                     | ((unsigned)((wc1 - wc0) << 3) << 11)            // dc8: 0 or 8
                     | ((unsigned)((hc1 - hc0) << 7) << 15);           // dr128: 0 or 128
            } else {
                // packed clamped GLOBAL coords for the cheap slow path
                ridx = (unsigned)hc0 | ((unsigned)wc0 << 7)
                     | ((unsigned)(hc1 - hc0) << 15) | ((unsigned)(wc1 - wc0) << 16)
                     | 0x80000000u;
            }
        }
        smwp[task] = make_uint2(rw0, rw1);
        smidx[task] = ridx;
    }
    __syncthreads();

    // ---------- phase B: table-driven gather, 8 thr/pixel ----------
    const int px = tid >> 3;            // 0..63 pixel in tile
    const int c  = tid & 7;             // 8-channel chunk
    const int hh = h0 + (px >> 3), ww = w0 + (px & 7);
    if (hh >= H_) return;
    const int pixg = (hh * W_ + ww) * G_ + g;
    const int tb = px * 9;

    __half2 acc[3][4];
#pragma unroll
    for (int gr = 0; gr < 3; ++gr)
#pragma unroll
        for (int u = 0; u < 4; ++u) acc[gr][u] = __half2(__half(0.f), __half(0.f));

#define FMA4(V, WT, GR)                                                       \
    {                                                                         \
        acc[GR][0] = __hfma2(*(const __half2*)&(V).x, (WT), acc[GR][0]);      \
        acc[GR][1] = __hfma2(*(const __half2*)&(V).y, (WT), acc[GR][1]);      \
        acc[GR][2] = __hfma2(*(const __half2*)&(V).z, (WT), acc[GR][2]);      \
        acc[GR][3] = __hfma2(*(const __half2*)&(V).w, (WT), acc[GR][3]);      \
    }

#define GC(GR, HC, WC, WT)                                                    \
    {                                                                         \
        const float* s_ = x + (size_t)((HC) * W_ + (WC)) * (G_ * C_) + g * C_ + c * 8; \
        const float4 v0 = *(const float4*)s_;                                 \
        const float4 v1 = *(const float4*)(s_ + 4);                           \
        __half2 e0 = __floats2half2_rn(v0.x, v0.y), e1 = __floats2half2_rn(v0.z, v0.w); \
        __half2 e2 = __floats2half2_rn(v1.x, v1.y), e3 = __floats2half2_rn(v1.z, v1.w); \
        acc[GR][0] = __hfma2(e0, (WT), acc[GR][0]);                           \
        acc[GR][1] = __hfma2(e1, (WT), acc[GR][1]);                           \
        acc[GR][2] = __hfma2(e2, (WT), acc[GR][2]);                           \
        acc[GR][3] = __hfma2(e3, (WT), acc[GR][3]);                           \
    }

#define TAP(KK)                                                               \
    {                                                                         \
        const unsigned ridx_ = smidx[tb + (KK)];                              \
        const uint2    rwp_  = smwp[tb + (KK)];                               \
        const __half2 wa_ = *(const __half2*)&rwp_.x;                         \
        const __half2 wb_ = *(const __half2*)&rwp_.y;                         \
        const __half2 W00 = __half2half2(__low2half(wa_));                    \
        const __half2 W01 = __half2half2(__high2half(wa_));                   \
        const __half2 W10 = __half2half2(__low2half(wb_));                    \
        const __half2 W11 = __half2half2(__high2half(wb_));                   \
        if (__builtin_expect((ridx_ >> 31) == 0u, 1)) {                       \
            const int i00_ = (int)(ridx_ & 0x7ffu) + c;                       \
            const int dc8_   = (int)((ridx_ >> 11) & 0xfu);                   \
            const int dr128_ = (int)((ridx_ >> 15) & 0xffu);                  \
            const int i01_ = i00_ + dc8_;                                     \
            const int i10_ = i00_ + dr128_;                                   \
            const int i11_ = i10_ + dc8_;                                     \
            const uint4 vA_ = smx[i00_];                                      \
            const uint4 vB_ = smx[i01_];                                      \
            const uint4 vC_ = smx[i10_];                                      \
            const uint4 vD_ = smx[i11_];                                      \
            FMA4(vA_, W00, (KK) / 3)                                          \
            FMA4(vB_, W01, (KK) / 3)                                          \
            FMA4(vC_, W10, (KK) / 3)                                          \
            FMA4(vD_, W11, (KK) / 3)                                          \
        } else {                                                              \
            const int hc0_ = (int)(ridx_ & 0x7fu);                            \
            const int wc0_ = (int)((ridx_ >> 7) & 0xffu);                     \
            const int hc1_ = hc0_ + (int)((ridx_ >> 15) & 1u);                \
            const int wc1_ = wc0_ + (int)((ridx_ >> 16) & 1u);                \
            GC((KK) / 3, hc0_, wc0_, W00)                                     \
            GC((KK) / 3, hc0_, wc1_, W01)                                     \
            GC((KK) / 3, hc1_, wc0_, W10)                                     \
            GC((KK) / 3, hc1_, wc1_, W11)                                     \
        }                                                                     \
    }

    TAP(0) TAP(1) TAP(2)
    TAP(3) TAP(4) TAP(5)
    TAP(6) TAP(7) TAP(8)

#undef TAP
#undef GC
#undef FMA4

    // fold 3 f16 groups in f32; thread writes its 8 channels (2x float4)
    float* op = out + (size_t)pixg * C_ + c * 8;
    {
        const float2 s0 = __half22float2(acc[0][0]);
        const float2 a0 = __half22float2(acc[1][0]);
        const float2 b0 = __half22float2(acc[2][0]);
        const float2 s1 = __half22float2(acc[0][1]);
        const float2 a1 = __half22float2(acc[1][1]);
        const float2 b1 = __half22float2(acc[2][1]);
        const float2 s2 = __half22float2(acc[0][2]);
        const float2 a2 = __half22float2(acc[1][2]);
        const float2 b2 = __half22float2(acc[2][2]);
        const float2 s3 = __half22float2(acc[0][3]);
        const float2 a3 = __half22float2(acc[1][3]);
        const float2 b3 = __half22float2(acc[2][3]);
        float4 o1, o2;
        o1.x = s0.x + a0.x + b0.x;  o1.y = s0.y + a0.y + b0.y;
        o1.z = s1.x + a1.x + b1.x;  o1.w = s1.y + a1.y + b1.y;
        o2.x = s2.x + a2.x + b2.x;  o2.y = s2.y + a2.y + b2.y;
        o2.z = s3.x + a3.x + b3.x;  o2.w = s3.y + a3.y + b3.y;
        *(float4*)op       = o1;
        *(float4*)(op + 4) = o2;
    }
}

extern "C" void kernel_launch(void* const* d_in, const int* in_sizes, int n_in,
                              void* d_out, int out_size, void* d_ws, size_t ws_size,
                              hipStream_t stream) {
    const float* x      = (const float*)d_in[0];
    const float* offset = (const float*)d_in[1];
    const float* mask   = (const float*)d_in[2];
    float* out          = (float*)d_out;

    // 13x20 tiles x 8 groups = 2080 blocks of 512 threads
    dcn_kernel<<<2080, 512, 0, stream>>>(x, offset, mask, out);
}

// Round 23
// 27.329 us; speedup vs baseline: 1.3626x; 1.0013x over previous
//
#include <hip/hip_runtime.h>
#include <hip/hip_fp16.h>

#define G_ 8
#define C_ 64
#define K_ 9
#define H_ 100
#define W_ 160
#define TW_ 8
#define TH_ 8
#define HALO_ 4
#define SW_ 16
#define SH_ 16
#define NXP_ 2048                  // 256 recs x 8 chunks, uint4 each = 32768 B

// R22 + epilogue trim: fold the 3 f16 accumulator groups IN F16 (8 v_pk_add
// _f16) then convert once to f32 (16 cvt) -- replaces 48 cvt + 32 f32 adds
// (~55 VALU ops/thread saved). Groups still bound f16 FMA chains to <=12;
// the 2 extra f16 adds keep absmax well under threshold. Also smxc = smx+c
// pointer hoists the per-tap +c add. Everything else identical to R22:
// [rec][c] row-major x planes (octet -> banks 4c, conflict-free), tap table
// with cheap global fallback, 39.7 KB LDS -> 4 blocks/CU, 32 waves/CU.
__global__ __launch_bounds__(512, 8) void dcn_kernel(
    const float* __restrict__ x,      // [H,W,G*C] f32
    const float* __restrict__ offset, // [H,W,G*K*2]
    const float* __restrict__ mask,   // [H,W,G*K]
    float* __restrict__ out)          // [H,W,G*C]
{
    __shared__ uint4 smx[NXP_];
    __shared__ uint2 smwp[576];
    __shared__ unsigned smidx[576];

    const int bid = (int)blockIdx.x;
    const int g   = bid & 7;          // group -> XCD round-robin (L2 partition)
    const int t   = bid >> 3;         // 0..259 tile (13 rows x 20 cols)
    const int th  = t / 20, twc = t % 20;
    const int h0  = th * TH_, w0 = twc * TW_;
    const int tid = (int)threadIdx.x;

    // ---------- stage x tile+halo: 256 recs x 8 chunks, edge-clamped ----------
#pragma unroll
    for (int it = 0; it < 4; ++it) {
        const int task = it * 512 + tid;
        const int rec  = task >> 3;
        const int c    = task & 7;
        const int i = rec >> 4, j = rec & 15;
        const int hs = min(max(h0 - HALO_ + i, 0), H_ - 1);
        const int ws = min(max(w0 - HALO_ + j, 0), W_ - 1);
        const float* src = x + (size_t)(hs * W_ + ws) * (G_ * C_) + g * C_ + c * 8;
        const float4 A = *(const float4*)src;
        const float4 B = *(const float4*)(src + 4);
        __half2 p0 = __floats2half2_rn(A.x, A.y);
        __half2 p1 = __floats2half2_rn(A.z, A.w);
        __half2 p2 = __floats2half2_rn(B.x, B.y);
        __half2 p3 = __floats2half2_rn(B.z, B.w);
        uint4 v;
        v.x = *(unsigned*)&p0; v.y = *(unsigned*)&p1;
        v.z = *(unsigned*)&p2; v.w = *(unsigned*)&p3;
        smx[task] = v;
    }

    // ---------- tap table: 576 tasks = 64 px x 9 taps, one task each ----------
    for (int task = tid; task < 576; task += 512) {
        const int px = task / 9;
        const int k  = task - px * 9;
        const int hh = h0 + (px >> 3), ww = w0 + (px & 7);
        unsigned rw0 = 0u, rw1 = 0u, ridx = 0u;
        if (hh < H_) {
            const int pixg = (hh * W_ + ww) * G_ + g;
            const float* mptr = mask + (size_t)pixg * K_;
            float mmax = -1e30f;
#pragma unroll
            for (int kk = 0; kk < K_; ++kk) mmax = fmaxf(mmax, mptr[kk]);
            float msum = 0.f;
#pragma unroll
            for (int kk = 0; kk < K_; ++kk) msum += __expf(mptr[kk] - mmax);
            const float m = __expf(mptr[k] - mmax) / msum;   // runtime k: global ptr only

            const float2 o2 = *(const float2*)(offset + (size_t)pixg * (2 * K_) + 2 * k);
            const float lh = (float)(hh + k / 3 - 1) + o2.x;
            const float lw = (float)(ww + k % 3 - 1) + o2.y;
            const float fh0 = floorf(lh), fw0 = floorf(lw);
            const float ft = lh - fh0, gt = lw - fw0;
            const int hI = (int)fh0, wI = (int)fw0;

            const float wh0 = (hI >= 0  && hI < H_    ) ? (1.f - ft) * m : 0.f;
            const float wh1 = (hI >= -1 && hI < H_ - 1) ? ft * m         : 0.f;
            const float cw0 = (wI >= 0  && wI < W_    ) ? (1.f - gt)     : 0.f;
            const float cw1 = (wI >= -1 && wI < W_ - 1) ? gt             : 0.f;
            __half2 wa = __floats2half2_rn(wh0 * cw0, wh0 * cw1);
            __half2 wb = __floats2half2_rn(wh1 * cw0, wh1 * cw1);
            rw0 = *(unsigned*)&wa;
            rw1 = *(unsigned*)&wb;

            const int hc0 = min(max(hI,     0), H_ - 1);
            const int hc1 = min(max(hI + 1, 0), H_ - 1);
            const int wc0 = min(max(wI,     0), W_ - 1);
            const int wc1 = min(max(wI + 1, 0), W_ - 1);

            const bool inbox = (hI >= h0 - HALO_) && (hI <= h0 + TH_ + HALO_ - 2) &&
                               (wI >= w0 - HALO_) && (wI <= w0 + TW_ + HALO_ - 2);
            if (inbox) {
                const int ri0 = hc0 - (h0 - HALO_);
                const int rj0 = wc0 - (w0 - HALO_);
                ridx = (unsigned)(ri0 * 128 + rj0 * 8)                 // base, 11 bits
                     | ((unsigned)((wc1 - wc0) << 3) << 11)            // dc8: 0 or 8
                     | ((unsigned)((hc1 - hc0) << 7) << 15);           // dr128: 0 or 128
            } else {
                // packed clamped GLOBAL coords for the cheap slow path
                ridx = (unsigned)hc0 | ((unsigned)wc0 << 7)
                     | ((unsigned)(hc1 - hc0) << 15) | ((unsigned)(wc1 - wc0) << 16)
                     | 0x80000000u;
            }
        }
        smwp[task] = make_uint2(rw0, rw1);
        smidx[task] = ridx;
    }
    __syncthreads();

    // ---------- phase B: table-driven gather, 8 thr/pixel ----------
    const int px = tid >> 3;            // 0..63 pixel in tile
    const int c  = tid & 7;             // 8-channel chunk
    const int hh = h0 + (px >> 3), ww = w0 + (px & 7);
    if (hh >= H_) return;
    const int pixg = (hh * W_ + ww) * G_ + g;
    const int tb = px * 9;
    const uint4* smxc = smx + c;        // fold +c into the base pointer

    __half2 acc[3][4];
#pragma unroll
    for (int gr = 0; gr < 3; ++gr)
#pragma unroll
        for (int u = 0; u < 4; ++u) acc[gr][u] = __half2(__half(0.f), __half(0.f));

#define FMA4(V, WT, GR)                                                       \
    {                                                                         \
        acc[GR][0] = __hfma2(*(const __half2*)&(V).x, (WT), acc[GR][0]);      \
        acc[GR][1] = __hfma2(*(const __half2*)&(V).y, (WT), acc[GR][1]);      \
        acc[GR][2] = __hfma2(*(const __half2*)&(V).z, (WT), acc[GR][2]);      \
        acc[GR][3] = __hfma2(*(const __half2*)&(V).w, (WT), acc[GR][3]);      \
    }

#define GC(GR, HC, WC, WT)                                                    \
    {                                                                         \
        const float* s_ = x + (size_t)((HC) * W_ + (WC)) * (G_ * C_) + g * C_ + c * 8; \
        const float4 v0 = *(const float4*)s_;                                 \
        const float4 v1 = *(const float4*)(s_ + 4);                           \
        __half2 e0 = __floats2half2_rn(v0.x, v0.y), e1 = __floats2half2_rn(v0.z, v0.w); \
        __half2 e2 = __floats2half2_rn(v1.x, v1.y), e3 = __floats2half2_rn(v1.z, v1.w); \
        acc[GR][0] = __hfma2(e0, (WT), acc[GR][0]);                           \
        acc[GR][1] = __hfma2(e1, (WT), acc[GR][1]);                           \
        acc[GR][2] = __hfma2(e2, (WT), acc[GR][2]);                           \
        acc[GR][3] = __hfma2(e3, (WT), acc[GR][3]);                           \
    }

#define TAP(KK)                                                               \
    {                                                                         \
        const unsigned ridx_ = smidx[tb + (KK)];                              \
        const uint2    rwp_  = smwp[tb + (KK)];                               \
        const __half2 wa_ = *(const __half2*)&rwp_.x;                         \
        const __half2 wb_ = *(const __half2*)&rwp_.y;                         \
        const __half2 W00 = __half2half2(__low2half(wa_));                    \
        const __half2 W01 = __half2half2(__high2half(wa_));                   \
        const __half2 W10 = __half2half2(__low2half(wb_));                    \
        const __half2 W11 = __half2half2(__high2half(wb_));                   \
        if (__builtin_expect((ridx_ >> 31) == 0u, 1)) {                       \
            const int i00_ = (int)(ridx_ & 0x7ffu);                           \
            const int dc8_   = (int)((ridx_ >> 11) & 0xfu);                   \
            const int dr128_ = (int)((ridx_ >> 15) & 0xffu);                  \
            const int i01_ = i00_ + dc8_;                                     \
            const int i10_ = i00_ + dr128_;                                   \
            const int i11_ = i10_ + dc8_;                                     \
            const uint4 vA_ = smxc[i00_];                                     \
            const uint4 vB_ = smxc[i01_];                                     \
            const uint4 vC_ = smxc[i10_];                                     \
            const uint4 vD_ = smxc[i11_];                                     \
            FMA4(vA_, W00, (KK) / 3)                                          \
            FMA4(vB_, W01, (KK) / 3)                                          \
            FMA4(vC_, W10, (KK) / 3)                                          \
            FMA4(vD_, W11, (KK) / 3)                                          \
        } else {                                                              \
            const int hc0_ = (int)(ridx_ & 0x7fu);                            \
            const int wc0_ = (int)((ridx_ >> 7) & 0xffu);                     \
            const int hc1_ = hc0_ + (int)((ridx_ >> 15) & 1u);                \
            const int wc1_ = wc0_ + (int)((ridx_ >> 16) & 1u);                \
            GC((KK) / 3, hc0_, wc0_, W00)                                     \
            GC((KK) / 3, hc0_, wc1_, W01)                                     \
            GC((KK) / 3, hc1_, wc0_, W10)                                     \
            GC((KK) / 3, hc1_, wc1_, W11)                                     \
        }                                                                     \
    }

    TAP(0) TAP(1) TAP(2)
    TAP(3) TAP(4) TAP(5)
    TAP(6) TAP(7) TAP(8)

#undef TAP
#undef GC
#undef FMA4

    // fold 3 f16 groups IN F16 (2 pk-adds after <=12-FMA chains), cvt once
    const __half2 f0 = __hadd2(__hadd2(acc[0][0], acc[1][0]), acc[2][0]);
    const __half2 f1 = __hadd2(__hadd2(acc[0][1], acc[1][1]), acc[2][1]);
    const __half2 f2 = __hadd2(__hadd2(acc[0][2], acc[1][2]), acc[2][2]);
    const __half2 f3 = __hadd2(__hadd2(acc[0][3], acc[1][3]), acc[2][3]);
    const float2 r0 = __half22float2(f0);
    const float2 r1 = __half22float2(f1);
    const float2 r2 = __half22float2(f2);
    const float2 r3 = __half22float2(f3);

    float* op = out + (size_t)pixg * C_ + c * 8;
    *(float4*)op       = make_float4(r0.x, r0.y, r1.x, r1.y);
    *(float4*)(op + 4) = make_float4(r2.x, r2.y, r3.x, r3.y);
}

extern "C" void kernel_launch(void* const* d_in, const int* in_sizes, int n_in,
                              void* d_out, int out_size, void* d_ws, size_t ws_size,
                              hipStream_t stream) {
    const float* x      = (const float*)d_in[0];
    const float* offset = (const float*)d_in[1];
    const float* mask   = (const float*)d_in[2];
    float* out          = (float*)d_out;

    // 13x20 tiles x 8 groups = 2080 blocks of 512 threads
    dcn_kernel<<<2080, 512, 0, stream>>>(x, offset, mask, out);
}